// Round 7
// baseline (536.911 us; speedup 1.0000x reference)
//
#include <hip/hip_runtime.h>

// Shapes (fixed by the problem)
#define LL 192
#define FF 2048

typedef __attribute__((__ext_vector_type__(8)))  __bf16 bf16x8;
typedef __attribute__((__ext_vector_type__(4)))  __bf16 bf16x4;
typedef __attribute__((__ext_vector_type__(4)))  float  f32x4;

#define MFMA16(a, b, c) __builtin_amdgcn_mfma_f32_16x16x32_bf16((a), (b), (c), 0, 0, 0)

// Empirical gfx950 laws (R1-R6 evidence):
//  - VGPR budget ~= 256 / (launch_bounds 2nd arg), any block size.
//  - Waves/SIMD steps down at vgpr > {64,128,256}; >256 total -> 1 wave/SIMD.
//  - Co-residency of >256-thread workgroups is unreliable (R6: 384thr/64.5KB
//    -> 1 block/CU).  256-thr blocks with small LDS co-schedule fine (R4).
//  - Barriers serialize pipes when only one block is resident -> prefer
//    barrier-free kernels (per-wave-complete work) where possible.

// ---------------------------------------------------------------------------
// Kernel 1: fused projection + prep.
//   blocks 0..1151  : y = X @ fc0_w^T + fc0_b -> kfragA / qfrag16 (MFMA
//                     fragment order; fc0_w converted from f32 in-block).
//   blocks 1152..1311: sig16 (16x16 C-reg order), bf16 fc2_w, MLP constants.
// ---------------------------------------------------------------------------
__launch_bounds__(256, 2)
__global__ void proj_prep_kernel(const float* __restrict__ qf_in,
                                 const float* __restrict__ gf_in,
                                 const float* __restrict__ fc0w,
                                 const float* __restrict__ fc0b,
                                 const float* __restrict__ se,
                                 const float* __restrict__ fc2w,
                                 const float* __restrict__ fc2b,
                                 const float* __restrict__ bn2g,
                                 const float* __restrict__ bn2b,
                                 const float* __restrict__ fc3w,
                                 __bf16* __restrict__ kfragA,
                                 __bf16* __restrict__ qfrag16,
                                 __bf16* __restrict__ sig16,
                                 __bf16* __restrict__ fc2w_bf,
                                 float* __restrict__ h2,
                                 float* __restrict__ bb2,
                                 float* __restrict__ f3)
{
    int bx = blockIdx.x, tid = threadIdx.x;
    if (bx >= 1152) {
        int i0 = (bx - 1152) * 256 + tid;
        const int stride = 160 * 256;
        const float c1 = rsqrtf(1.f + 1e-5f);
        for (int i = i0; i < LL * LL; i += stride) {
            int r = i & 3, lane = (i >> 2) & 63, tile = i >> 8;
            int jt = tile % 12, st = tile / 12;
            int s = st * 16 + (lane >> 4) * 4 + r;
            int t = jt * 16 + (lane & 15);
            sig16[i] = (__bf16)(1.f / (1.f + __expf(-se[s * 192 + t])));
        }
        for (int i = i0; i < FF * LL; i += stride)
            fc2w_bf[i] = (__bf16)fc2w[i];
        for (int i = i0; i < FF; i += stride) {
            float h = bn2g[i] * c1;
            h2[i]  = h;
            bb2[i] = fc2b[i] * h + bn2b[i];
            f3[i]  = fc3w[i];
        }
        return;
    }
    __shared__ __bf16 Xs[32][136];
    __shared__ __bf16 Ws[128][136];
    __shared__ __bf16 Os[4096];          // 32 rows x 128, fragment order
    const float* src = (bx < 384) ? (qf_in + (size_t)bx * (32 * 128))
                                  : (gf_in + (size_t)(bx - 384) * (32 * 128));
#pragma unroll
    for (int it = 0; it < 4; ++it) {
        int e = (it * 256 + tid) * 4;
        int r = e >> 7, c = e & 127;
        float4 v = *reinterpret_cast<const float4*>(src + e);
        bf16x4 xv;
        xv[0] = (__bf16)v.x; xv[1] = (__bf16)v.y;
        xv[2] = (__bf16)v.z; xv[3] = (__bf16)v.w;
        *reinterpret_cast<bf16x4*>(&Xs[r][c]) = xv;
    }
#pragma unroll
    for (int it = 0; it < 16; ++it) {    // fc0_w f32 -> bf16 in LDS
        int e = (it * 256 + tid) * 4;
        int r = e >> 7, c = e & 127;
        float4 v = *reinterpret_cast<const float4*>(fc0w + e);
        bf16x4 xv;
        xv[0] = (__bf16)v.x; xv[1] = (__bf16)v.y;
        xv[2] = (__bf16)v.z; xv[3] = (__bf16)v.w;
        *reinterpret_cast<bf16x4*>(&Ws[r][c]) = xv;
    }
    __syncthreads();

    int wv = tid >> 6, lane = tid & 63, quad = lane >> 4, l16 = lane & 15;
    int n0 = wv * 32;
    f32x4 acc[2][2];
#pragma unroll
    for (int m = 0; m < 2; ++m)
#pragma unroll
        for (int n = 0; n < 2; ++n) acc[m][n] = (f32x4){0.f, 0.f, 0.f, 0.f};
#pragma unroll
    for (int ks = 0; ks < 4; ++ks) {
        bf16x8 a0 = *reinterpret_cast<const bf16x8*>(&Xs[l16][ks * 32 + quad * 8]);
        bf16x8 a1 = *reinterpret_cast<const bf16x8*>(&Xs[16 + l16][ks * 32 + quad * 8]);
        bf16x8 b0 = *reinterpret_cast<const bf16x8*>(&Ws[n0 + l16][ks * 32 + quad * 8]);
        bf16x8 b1 = *reinterpret_cast<const bf16x8*>(&Ws[n0 + 16 + l16][ks * 32 + quad * 8]);
        acc[0][0] = MFMA16(a0, b0, acc[0][0]);
        acc[0][1] = MFMA16(a0, b1, acc[0][1]);
        acc[1][0] = MFMA16(a1, b0, acc[1][0]);
        acc[1][1] = MFMA16(a1, b1, acc[1][1]);
    }
#pragma unroll
    for (int mt = 0; mt < 2; ++mt)
#pragma unroll
        for (int nt = 0; nt < 2; ++nt) {
            int d = n0 + nt * 16 + l16;
            float bv = fc0b[d];
            int abase = mt * 2048 + (d >> 5) * 512 + ((d >> 3) & 3) * 128 + (d & 7);
#pragma unroll
            for (int r = 0; r < 4; ++r)
                Os[abase + (quad * 4 + r) * 8] = (__bf16)(acc[mt][nt][r] + bv);
        }
    __syncthreads();

    int row0 = bx * 32;
    __bf16* dst;
    if (bx < 384) {
        int qi = row0 / 192, tg0 = (row0 % 192) >> 4;
        dst = qfrag16 + qi * 24576 + tg0 * 2048;
    } else {
        int rk0 = row0 - 12288;
        int ki = rk0 / 192, sg0 = (rk0 % 192) >> 4;
        dst = kfragA + ki * 24576 + sg0 * 2048;
    }
#pragma unroll
    for (int it = 0; it < 2; ++it) {
        int e = (it * 256 + tid) * 8;
        *reinterpret_cast<bf16x8*>(dst + e) =
            *reinterpret_cast<const bf16x8*>(&Os[e]);
    }
}

// ---------------------------------------------------------------------------
// Kernel 2: per-pair score GEMM + sigmoid-modulation + dual max-reduce.
//    BARRIER-FREE, LDS-FREE.  256 threads = 4 waves; wave w fully owns pairs
//    (kbase + 2w) and (kbase + 2w + 1): computes the whole 192x192 score for
//    each, so both max-reductions complete inside the wave (shuffles only).
//    A (key) and B (query) fragments stream from L2 in fragment order
//    (contiguous 1 KB/instruction); sig from sig16 in C-register order.
//    s processed in 4 groups of 48 (acc[3][3] = 36 VGPRs), t in 4 quarters.
//    ~118 VGPRs < 128 budget from (256,2) -> no spill; no LDS -> up to
//    4 blocks/CU, 16 independent waves, full pipe overlap.
// ---------------------------------------------------------------------------
__launch_bounds__(256, 2)
__global__ void score_kernel(const __bf16* __restrict__ kfragA,
                             const __bf16* __restrict__ qfrag16,
                             const __bf16* __restrict__ sig16,
                             const float* __restrict__ bn1g,
                             const float* __restrict__ bn1b,
                             __bf16* __restrict__ Sred)
{
    int tid = threadIdx.x;
    int q = blockIdx.x & 63;
    int kbase = (blockIdx.x >> 6) << 3;
    int w = tid >> 6, lane = tid & 63, quad = lane >> 4, l16 = lane & 15;
    const float g1c = bn1g[0] * rsqrtf(1.f + 1e-5f);
    const float b1v = bn1b[0];
    const __bf16* qbase = qfrag16 + (size_t)q * 24576 + lane * 8;

    for (int pp = 0; pp < 2; ++pp) {
        int kidx = kbase + 2 * w + pp;
        const __bf16* kp = kfragA + (size_t)kidx * 24576 + lane * 8;
        size_t ob = (size_t)(q * 128 + kidx) * 384;

        float cmv[12];
#pragma unroll
        for (int jt = 0; jt < 12; ++jt) cmv[jt] = -3.0e38f;

        for (int sg = 0; sg < 4; ++sg) {        // s-groups of 48 rows
            float rm[3][4];
#pragma unroll
            for (int i = 0; i < 3; ++i)
#pragma unroll
                for (int r = 0; r < 4; ++r) rm[i][r] = -3.0e38f;

#pragma unroll
            for (int qt = 0; qt < 4; ++qt) {    // t-quarters of 48 cols
                bf16x4 sgv[3][3];
#pragma unroll
                for (int i = 0; i < 3; ++i)
#pragma unroll
                    for (int j = 0; j < 3; ++j)
                        sgv[i][j] = *reinterpret_cast<const bf16x4*>(
                            sig16 + ((size_t)((3 * sg + i) * 12 + qt * 3 + j) * 64
                                     + lane) * 4);

                f32x4 acc[3][3];
#pragma unroll
                for (int i = 0; i < 3; ++i)
#pragma unroll
                    for (int j = 0; j < 3; ++j)
                        acc[i][j] = (f32x4){0.f, 0.f, 0.f, 0.f};

#pragma unroll
                for (int ks = 0; ks < 4; ++ks) {
                    bf16x8 a[3];
#pragma unroll
                    for (int i = 0; i < 3; ++i)
                        a[i] = *reinterpret_cast<const bf16x8*>(
                            kp + ((3 * sg + i) * 4 + ks) * 512);
#pragma unroll
                    for (int j = 0; j < 3; ++j) {
                        bf16x8 b = *reinterpret_cast<const bf16x8*>(
                            qbase + ((qt * 3 + j) * 4 + ks) * 512);
#pragma unroll
                        for (int i = 0; i < 3; ++i)
                            acc[i][j] = MFMA16(a[i], b, acc[i][j]);
                    }
                }

                // epilogue: v = acc*sig; s = 48sg+16i+quad*4+r, t = (3qt+j)*16+l16
#pragma unroll
                for (int j = 0; j < 3; ++j) {
                    float cj = -3.0e38f;
#pragma unroll
                    for (int i = 0; i < 3; ++i) {
                        float v0 = acc[i][j][0] * (float)sgv[i][j][0];
                        float v1 = acc[i][j][1] * (float)sgv[i][j][1];
                        float v2 = acc[i][j][2] * (float)sgv[i][j][2];
                        float v3 = acc[i][j][3] * (float)sgv[i][j][3];
                        rm[i][0] = fmaxf(rm[i][0], v0);
                        rm[i][1] = fmaxf(rm[i][1], v1);
                        rm[i][2] = fmaxf(rm[i][2], v2);
                        rm[i][3] = fmaxf(rm[i][3], v3);
                        cj = fmaxf(cj, fmaxf(fmaxf(v0, v1), fmaxf(v2, v3)));
                    }
                    cmv[qt * 3 + j] = fmaxf(cmv[qt * 3 + j], cj);
                }
            }

            // max over t complete for these 48 s: reduce across l16 lanes
#pragma unroll
            for (int i = 0; i < 3; ++i)
#pragma unroll
                for (int r = 0; r < 4; ++r) {
                    float v = rm[i][r];
                    v = fmaxf(v, __shfl_xor(v, 1, 64));
                    v = fmaxf(v, __shfl_xor(v, 2, 64));
                    v = fmaxf(v, __shfl_xor(v, 4, 64));
                    v = fmaxf(v, __shfl_xor(v, 8, 64));
                    rm[i][r] = v;
                }
            if (l16 == 0) {
#pragma unroll
                for (int i = 0; i < 3; ++i) {
                    bf16x4 pk;
                    pk[0] = (__bf16)(rm[i][0] * g1c + b1v);
                    pk[1] = (__bf16)(rm[i][1] * g1c + b1v);
                    pk[2] = (__bf16)(rm[i][2] * g1c + b1v);
                    pk[3] = (__bf16)(rm[i][3] * g1c + b1v);
                    *reinterpret_cast<bf16x4*>(
                        &Sred[ob + 192 + 48 * sg + 16 * i + quad * 4]) = pk;
                }
            }
        }

        // max over s complete for all 192 t: combine the 4 quads
#pragma unroll
        for (int jt = 0; jt < 12; ++jt) {
            float v = cmv[jt];
            v = fmaxf(v, __shfl_xor(v, 16, 64));
            v = fmaxf(v, __shfl_xor(v, 32, 64));
            if (lane < 16)
                Sred[ob + jt * 16 + lane] = (__bf16)(v * g1c + b1v);
        }
    }
}

// ---------------------------------------------------------------------------
// Kernel 3: fused fc2 + bn2 + relu + fc3 + pair-sum + bn3.  64 Sred rows per
//    block, 8 waves x 256 ff-cols.  grid 256 = 1 block/CU, (512,1) -> full
//    256-reg budget, af[4][6]=96 regs hoisted, no spill.
// ---------------------------------------------------------------------------
__launch_bounds__(512, 1)
__global__ void mlp_kernel(const __bf16* __restrict__ Sred,
                           const __bf16* __restrict__ fc2w_bf,
                           const float* __restrict__ h2,
                           const float* __restrict__ bb2,
                           const float* __restrict__ f3,
                           const float* __restrict__ fc3b,
                           const float* __restrict__ bn3g,
                           const float* __restrict__ bn3b,
                           float* __restrict__ out)
{
    __shared__ __bf16 As[64][200];
    __shared__ float  psum_lds[8][64];
    int bx = blockIdx.x, tid = threadIdx.x;
    const __bf16* asrc = Sred + (size_t)bx * (64 * 192);
#pragma unroll
    for (int it = 0; it < 3; ++it) {
        int e = (it * 512 + tid) * 8;
        int r = e / 192, c = e - r * 192;
        *reinterpret_cast<bf16x8*>(&As[r][c]) =
            *reinterpret_cast<const bf16x8*>(asrc + e);
    }
    __syncthreads();

    int wv = tid >> 6, lane = tid & 63, quad = lane >> 4, l16 = lane & 15;
    bf16x8 af[4][6];
#pragma unroll
    for (int m = 0; m < 4; ++m)
#pragma unroll
        for (int kk = 0; kk < 6; ++kk)
            af[m][kk] = *reinterpret_cast<const bf16x8*>(
                &As[m * 16 + l16][kk * 32 + quad * 8]);

    float ps[4][4] = {{0.f,0.f,0.f,0.f},{0.f,0.f,0.f,0.f},
                      {0.f,0.f,0.f,0.f},{0.f,0.f,0.f,0.f}};
    for (int nt = 0; nt < 16; ++nt) {
        int n0 = wv * 256 + nt * 16;
        f32x4 acc[4];
#pragma unroll
        for (int m = 0; m < 4; ++m) acc[m] = (f32x4){0.f, 0.f, 0.f, 0.f};
        const __bf16* bp = fc2w_bf + (size_t)(n0 + l16) * 192 + quad * 8;
#pragma unroll
        for (int kk = 0; kk < 6; ++kk) {
            bf16x8 b = *reinterpret_cast<const bf16x8*>(bp + kk * 32);
#pragma unroll
            for (int m = 0; m < 4; ++m) acc[m] = MFMA16(af[m][kk], b, acc[m]);
        }
        int n = n0 + l16;
        float hh = h2[n], bb = bb2[n], ffv = f3[n];
#pragma unroll
        for (int m = 0; m < 4; ++m)
#pragma unroll
            for (int r = 0; r < 4; ++r)
                ps[m][r] += fmaxf(acc[m][r] * hh + bb, 0.f) * ffv;
    }
#pragma unroll
    for (int m = 0; m < 4; ++m)
#pragma unroll
        for (int r = 0; r < 4; ++r) {
            float v = ps[m][r];
            v += __shfl_xor(v, 1, 64);
            v += __shfl_xor(v, 2, 64);
            v += __shfl_xor(v, 4, 64);
            v += __shfl_xor(v, 8, 64);
            if (l16 == 0) psum_lds[wv][m * 16 + quad * 4 + r] = v;
        }
    __syncthreads();
    if (tid < 32) {
        float s = 0.f;
#pragma unroll
        for (int w = 0; w < 8; ++w)
            s += psum_lds[w][2 * tid] + psum_lds[w][2 * tid + 1];
        const float c1 = rsqrtf(1.f + 1e-5f);
        out[bx * 32 + tid] = (s + 2.f * fc3b[0]) * (bn3g[0] * c1) + bn3b[0];
    }
}

// ---------------------------------------------------------------------------
extern "C" void kernel_launch(void* const* d_in, const int* in_sizes, int n_in,
                              void* d_out, int out_size, void* d_ws, size_t ws_size,
                              hipStream_t stream)
{
    const float* q_feat = (const float*)d_in[0];
    const float* g_feat = (const float*)d_in[1];
    const float* se     = (const float*)d_in[2];
    const float* fc0w   = (const float*)d_in[3];
    const float* fc0b   = (const float*)d_in[4];
    const float* fc2w   = (const float*)d_in[5];
    const float* fc2b   = (const float*)d_in[6];
    const float* fc3w   = (const float*)d_in[7];
    const float* fc3b   = (const float*)d_in[8];
    const float* bn1g   = (const float*)d_in[9];
    const float* bn1b   = (const float*)d_in[10];
    const float* bn2g   = (const float*)d_in[11];
    const float* bn2b   = (const float*)d_in[12];
    const float* bn3g   = (const float*)d_in[13];
    const float* bn3b   = (const float*)d_in[14];
    float* out = (float*)d_out;

    char* ws = (char*)d_ws;
    __bf16* kfragA   = (__bf16*)(ws);                 //  6,291,456 B
    __bf16* qfrag16  = (__bf16*)(ws +  6291456);      //  3,145,728 B
    __bf16* sig16    = (__bf16*)(ws +  9437184);      //     73,728 B
    __bf16* fc2w_bf  = (__bf16*)(ws +  9543680);      //    786,432 B
    float*  h2       = (float*) (ws + 10330112);      //      8,192 B
    float*  bb2      = (float*) (ws + 10338304);      //      8,192 B
    float*  f3       = (float*) (ws + 10346496);      //      8,192 B
    __bf16* Sred     = (__bf16*)(ws + 10354688);      //  6,291,456 B (16.65 MB total)

    proj_prep_kernel<<<1312, 256, 0, stream>>>(q_feat, g_feat, fc0w, fc0b, se,
                                               fc2w, fc2b, bn2g, bn2b, fc3w,
                                               kfragA, qfrag16, sig16, fc2w_bf,
                                               h2, bb2, f3);
    score_kernel<<<1024, 256, 0, stream>>>(kfragA, qfrag16, sig16, bn1g, bn1b, Sred);
    mlp_kernel<<<256, 512, 0, stream>>>(Sred, fc2w_bf, h2, bb2, f3,
                                        fc3b, bn3g, bn3b, out);
}

// Round 8
// 249.904 us; speedup vs baseline: 2.1485x; 2.1485x over previous
//
#include <hip/hip_runtime.h>

// Shapes (fixed by the problem)
#define LL 192
#define FF 2048

typedef __attribute__((__ext_vector_type__(8)))  __bf16 bf16x8;
typedef __attribute__((__ext_vector_type__(4)))  __bf16 bf16x4;
typedef __attribute__((__ext_vector_type__(4)))  float  f32x4;

#define MFMA16(a, b, c) __builtin_amdgcn_mfma_f32_16x16x32_bf16((a), (b), (c), 0, 0, 0)

// Empirical gfx950 laws (R1-R7 evidence):
//  - VGPR budget ~= 256 / (launch_bounds 2nd arg), any block size.
//  - VGPR_Count == budget means the cap was HIT -> suspect spill (R4: 232MB,
//    R7: 365MB scratch writes).  Keep ~10% headroom below the budget and pin
//    loops with "#pragma unroll 1" so the scheduler can't pipeline past it.
//  - 256-thr blocks with <=80KB LDS co-schedule 2/CU (R4); 384-thr don't (R6).
//  - Stream-shared operands MUST be staged once in LDS per block; per-wave L2
//    streaming duplicates traffic 4x and dies (R7).
//  - Hoist only small, iteration-invariant operands in registers (Q-frags:
//    48 regs amortized over 8 pairs).

// ---------------------------------------------------------------------------
// Kernel 1: fused projection + prep.
//   blocks 0..1151  : y = X @ fc0_w^T + fc0_b -> kfragA / qfrag16 (MFMA
//                     fragment order; fc0_w converted from f32 in-block).
//   blocks 1152..1311: sig16 (16x16 C-reg order), bf16 fc2_w, MLP constants.
// ---------------------------------------------------------------------------
__launch_bounds__(256, 2)
__global__ void proj_prep_kernel(const float* __restrict__ qf_in,
                                 const float* __restrict__ gf_in,
                                 const float* __restrict__ fc0w,
                                 const float* __restrict__ fc0b,
                                 const float* __restrict__ se,
                                 const float* __restrict__ fc2w,
                                 const float* __restrict__ fc2b,
                                 const float* __restrict__ bn2g,
                                 const float* __restrict__ bn2b,
                                 const float* __restrict__ fc3w,
                                 __bf16* __restrict__ kfragA,
                                 __bf16* __restrict__ qfrag16,
                                 __bf16* __restrict__ sig16,
                                 __bf16* __restrict__ fc2w_bf,
                                 float* __restrict__ h2,
                                 float* __restrict__ bb2,
                                 float* __restrict__ f3)
{
    int bx = blockIdx.x, tid = threadIdx.x;
    if (bx >= 1152) {
        int i0 = (bx - 1152) * 256 + tid;
        const int stride = 160 * 256;
        const float c1 = rsqrtf(1.f + 1e-5f);
        for (int i = i0; i < LL * LL; i += stride) {
            int r = i & 3, lane = (i >> 2) & 63, tile = i >> 8;
            int jt = tile % 12, st = tile / 12;
            int s = st * 16 + (lane >> 4) * 4 + r;
            int t = jt * 16 + (lane & 15);
            sig16[i] = (__bf16)(1.f / (1.f + __expf(-se[s * 192 + t])));
        }
        for (int i = i0; i < FF * LL; i += stride)
            fc2w_bf[i] = (__bf16)fc2w[i];
        for (int i = i0; i < FF; i += stride) {
            float h = bn2g[i] * c1;
            h2[i]  = h;
            bb2[i] = fc2b[i] * h + bn2b[i];
            f3[i]  = fc3w[i];
        }
        return;
    }
    __shared__ __bf16 Xs[32][136];
    __shared__ __bf16 Ws[128][136];
    __shared__ __bf16 Os[4096];          // 32 rows x 128, fragment order
    const float* src = (bx < 384) ? (qf_in + (size_t)bx * (32 * 128))
                                  : (gf_in + (size_t)(bx - 384) * (32 * 128));
#pragma unroll
    for (int it = 0; it < 4; ++it) {
        int e = (it * 256 + tid) * 4;
        int r = e >> 7, c = e & 127;
        float4 v = *reinterpret_cast<const float4*>(src + e);
        bf16x4 xv;
        xv[0] = (__bf16)v.x; xv[1] = (__bf16)v.y;
        xv[2] = (__bf16)v.z; xv[3] = (__bf16)v.w;
        *reinterpret_cast<bf16x4*>(&Xs[r][c]) = xv;
    }
#pragma unroll
    for (int it = 0; it < 16; ++it) {    // fc0_w f32 -> bf16 in LDS
        int e = (it * 256 + tid) * 4;
        int r = e >> 7, c = e & 127;
        float4 v = *reinterpret_cast<const float4*>(fc0w + e);
        bf16x4 xv;
        xv[0] = (__bf16)v.x; xv[1] = (__bf16)v.y;
        xv[2] = (__bf16)v.z; xv[3] = (__bf16)v.w;
        *reinterpret_cast<bf16x4*>(&Ws[r][c]) = xv;
    }
    __syncthreads();

    int wv = tid >> 6, lane = tid & 63, quad = lane >> 4, l16 = lane & 15;
    int n0 = wv * 32;
    f32x4 acc[2][2];
#pragma unroll
    for (int m = 0; m < 2; ++m)
#pragma unroll
        for (int n = 0; n < 2; ++n) acc[m][n] = (f32x4){0.f, 0.f, 0.f, 0.f};
#pragma unroll
    for (int ks = 0; ks < 4; ++ks) {
        bf16x8 a0 = *reinterpret_cast<const bf16x8*>(&Xs[l16][ks * 32 + quad * 8]);
        bf16x8 a1 = *reinterpret_cast<const bf16x8*>(&Xs[16 + l16][ks * 32 + quad * 8]);
        bf16x8 b0 = *reinterpret_cast<const bf16x8*>(&Ws[n0 + l16][ks * 32 + quad * 8]);
        bf16x8 b1 = *reinterpret_cast<const bf16x8*>(&Ws[n0 + 16 + l16][ks * 32 + quad * 8]);
        acc[0][0] = MFMA16(a0, b0, acc[0][0]);
        acc[0][1] = MFMA16(a0, b1, acc[0][1]);
        acc[1][0] = MFMA16(a1, b0, acc[1][0]);
        acc[1][1] = MFMA16(a1, b1, acc[1][1]);
    }
#pragma unroll
    for (int mt = 0; mt < 2; ++mt)
#pragma unroll
        for (int nt = 0; nt < 2; ++nt) {
            int d = n0 + nt * 16 + l16;
            float bv = fc0b[d];
            int abase = mt * 2048 + (d >> 5) * 512 + ((d >> 3) & 3) * 128 + (d & 7);
#pragma unroll
            for (int r = 0; r < 4; ++r)
                Os[abase + (quad * 4 + r) * 8] = (__bf16)(acc[mt][nt][r] + bv);
        }
    __syncthreads();

    int row0 = bx * 32;
    __bf16* dst;
    if (bx < 384) {
        int qi = row0 / 192, tg0 = (row0 % 192) >> 4;
        dst = qfrag16 + qi * 24576 + tg0 * 2048;
    } else {
        int rk0 = row0 - 12288;
        int ki = rk0 / 192, sg0 = (rk0 % 192) >> 4;
        dst = kfragA + ki * 24576 + sg0 * 2048;
    }
#pragma unroll
    for (int it = 0; it < 2; ++it) {
        int e = (it * 256 + tid) * 8;
        *reinterpret_cast<bf16x8*>(dst + e) =
            *reinterpret_cast<const bf16x8*>(&Os[e]);
    }
}

// ---------------------------------------------------------------------------
// Kernel 2: per-pair score GEMM + sigmoid-modulation + dual max-reduce.
//    256 threads = 4 waves.  Wave w owns the FIXED t-slice jt in {3w..3w+2}
//    (48 t-cols) for all 192 s of every pair:
//      - B (query) fragments hoisted in registers ONCE per block (48 VGPRs,
//        amortized over 8 pairs -> zero per-pair B traffic).
//      - A (key) fragments staged ONCE per pair into LDS (48 KB, shared by
//        all 4 waves -> 192 b128-reads/pair instead of R6's 288 + no re-read).
//      - sig streamed from L2 in C-register order (73 KB/pair, disjoint
//        per wave -> no duplication).
//    Row-max (over t): 2 xor-shuffles (DPP) + 4-class LDS scatter + combine.
//    Col-max (over s): fully in-wave (2 shuffles), direct global write.
//    ~120 VGPRs (budget 128 via (256,2)); LDS 55.6 KB -> 2 blocks/CU.
// ---------------------------------------------------------------------------
__launch_bounds__(256, 2)
__global__ void score_kernel(const __bf16* __restrict__ kfragA,
                             const __bf16* __restrict__ qfrag16,
                             const __bf16* __restrict__ sig16,
                             const float* __restrict__ bn1g,
                             const float* __restrict__ bn1b,
                             __bf16* __restrict__ Sred)
{
    __shared__ __bf16 Abuf[24576];      // 49,152 B: K fragments, current pair
    __shared__ __bf16 rowT4[16][200];   //  6,400 B: row-max partials
                                        //  [l16-class*4 + wave][s] (+pad)

    int tid = threadIdx.x;
    int q = blockIdx.x & 63;
    int kbase = (blockIdx.x >> 6) << 3;    // kg-major: kfragA L2 locality
    int w = tid >> 6, lane = tid & 63, quad = lane >> 4, l16 = lane & 15;
    const float g1c = bn1g[0] * rsqrtf(1.f + 1e-5f);
    const float b1v = bn1b[0];

    // Hoist B (query) fragments for this wave's t-slice: 12 x bf16x8 = 48 VGPR
    bf16x8 Bf[3][4];
    {
        const __bf16* qb = qfrag16 + (size_t)q * 24576 + lane * 8;
#pragma unroll
        for (int j = 0; j < 3; ++j)
#pragma unroll
            for (int ks = 0; ks < 4; ++ks)
                Bf[j][ks] = *reinterpret_cast<const bf16x8*>(
                    qb + ((3 * w + j) * 4 + ks) * 512);
    }

#pragma unroll 1
    for (int kk = 0; kk < 8; ++kk) {
        int kidx = kbase + kk;
        // stage K fragments (contiguous, lane-ordered -> conflict-free b128)
        const __bf16* kp = kfragA + (size_t)kidx * 24576;
#pragma unroll
        for (int it = 0; it < 12; ++it) {
            int e = (it * 256 + tid) * 8;
            *reinterpret_cast<bf16x8*>(&Abuf[e]) =
                *reinterpret_cast<const bf16x8*>(kp + e);
        }
        __syncthreads();   // Abuf ready; rowT4 from previous pair consumed

        size_t ob = (size_t)(q * 128 + kidx) * 384;
        float cm0 = -3.0e38f, cm1 = -3.0e38f, cm2 = -3.0e38f;

#pragma unroll 1
        for (int sc = 0; sc < 6; ++sc) {          // 32 s-rows per chunk
            f32x4 acc[2][3];
#pragma unroll
            for (int i = 0; i < 2; ++i)
#pragma unroll
                for (int j = 0; j < 3; ++j)
                    acc[i][j] = (f32x4){0.f, 0.f, 0.f, 0.f};

#pragma unroll
            for (int ks = 0; ks < 4; ++ks) {
                bf16x8 a0 = *reinterpret_cast<const bf16x8*>(
                    &Abuf[((sc * 2 + 0) * 4 + ks) * 512 + lane * 8]);
                bf16x8 a1 = *reinterpret_cast<const bf16x8*>(
                    &Abuf[((sc * 2 + 1) * 4 + ks) * 512 + lane * 8]);
#pragma unroll
                for (int j = 0; j < 3; ++j) {
                    acc[0][j] = MFMA16(a0, Bf[j][ks], acc[0][j]);
                    acc[1][j] = MFMA16(a1, Bf[j][ks], acc[1][j]);
                }
            }

            // epilogue: v = acc * sig;  s = sc*32+16i+quad*4+r, t = (3w+j)*16+l16
#pragma unroll
            for (int i = 0; i < 2; ++i) {
                float rm0 = -3.0e38f, rm1 = -3.0e38f, rm2 = -3.0e38f, rm3 = -3.0e38f;
#pragma unroll
                for (int j = 0; j < 3; ++j) {
                    bf16x4 sv = *reinterpret_cast<const bf16x4*>(
                        sig16 + ((size_t)((sc * 2 + i) * 12 + 3 * w + j) * 64
                                 + lane) * 4);
                    float v0 = acc[i][j][0] * (float)sv[0];
                    float v1 = acc[i][j][1] * (float)sv[1];
                    float v2 = acc[i][j][2] * (float)sv[2];
                    float v3 = acc[i][j][3] * (float)sv[3];
                    rm0 = fmaxf(rm0, v0); rm1 = fmaxf(rm1, v1);
                    rm2 = fmaxf(rm2, v2); rm3 = fmaxf(rm3, v3);
                    float cj = fmaxf(fmaxf(v0, v1), fmaxf(v2, v3));
                    if (j == 0) cm0 = fmaxf(cm0, cj);
                    else if (j == 1) cm1 = fmaxf(cm1, cj);
                    else cm2 = fmaxf(cm2, cj);
                }
                // reduce over l16 groups of 4 (xor 1,2 -> DPP quad_perm, VALU)
                rm0 = fmaxf(rm0, __shfl_xor(rm0, 1, 64));
                rm0 = fmaxf(rm0, __shfl_xor(rm0, 2, 64));
                rm1 = fmaxf(rm1, __shfl_xor(rm1, 1, 64));
                rm1 = fmaxf(rm1, __shfl_xor(rm1, 2, 64));
                rm2 = fmaxf(rm2, __shfl_xor(rm2, 1, 64));
                rm2 = fmaxf(rm2, __shfl_xor(rm2, 2, 64));
                rm3 = fmaxf(rm3, __shfl_xor(rm3, 1, 64));
                rm3 = fmaxf(rm3, __shfl_xor(rm3, 2, 64));
                if ((l16 & 3) == 0) {
                    bf16x4 pk;
                    pk[0] = (__bf16)rm0; pk[1] = (__bf16)rm1;
                    pk[2] = (__bf16)rm2; pk[3] = (__bf16)rm3;
                    *reinterpret_cast<bf16x4*>(
                        &rowT4[(l16 >> 2) * 4 + w][sc * 32 + 16 * i + quad * 4]) = pk;
                }
            }
        }

        // col-max (max over s, indexed by t): reduce over quad, direct write
        {
            float v0 = cm0, v1 = cm1, v2 = cm2;
            v0 = fmaxf(v0, __shfl_xor(v0, 16, 64));
            v0 = fmaxf(v0, __shfl_xor(v0, 32, 64));
            v1 = fmaxf(v1, __shfl_xor(v1, 16, 64));
            v1 = fmaxf(v1, __shfl_xor(v1, 32, 64));
            v2 = fmaxf(v2, __shfl_xor(v2, 16, 64));
            v2 = fmaxf(v2, __shfl_xor(v2, 32, 64));
            if (quad == 0) {
                Sred[ob + (3 * w + 0) * 16 + l16] = (__bf16)(v0 * g1c + b1v);
                Sred[ob + (3 * w + 1) * 16 + l16] = (__bf16)(v1 * g1c + b1v);
                Sred[ob + (3 * w + 2) * 16 + l16] = (__bf16)(v2 * g1c + b1v);
            }
        }
        __syncthreads();   // rowT4 complete

        // row-max combine (max over t, indexed by s)
        if (tid < 192) {
            float m1 = -3.0e38f;
#pragma unroll
            for (int c = 0; c < 16; ++c)
                m1 = fmaxf(m1, (float)rowT4[c][tid]);
            Sred[ob + 192 + tid] = (__bf16)(m1 * g1c + b1v);
        }
        // next iteration: staging writes Abuf (disjoint from rowT4); the
        // post-stage barrier fences rowT4 reads before its next overwrite.
    }
}

// ---------------------------------------------------------------------------
// Kernel 3: fused fc2 + bn2 + relu + fc3 + pair-sum + bn3.  64 Sred rows per
//    block, 8 waves x 256 ff-cols.  grid 256 = 1 block/CU, (512,1) -> full
//    256-reg budget, af[4][6]=96 regs hoisted, no spill.
// ---------------------------------------------------------------------------
__launch_bounds__(512, 1)
__global__ void mlp_kernel(const __bf16* __restrict__ Sred,
                           const __bf16* __restrict__ fc2w_bf,
                           const float* __restrict__ h2,
                           const float* __restrict__ bb2,
                           const float* __restrict__ f3,
                           const float* __restrict__ fc3b,
                           const float* __restrict__ bn3g,
                           const float* __restrict__ bn3b,
                           float* __restrict__ out)
{
    __shared__ __bf16 As[64][200];
    __shared__ float  psum_lds[8][64];
    int bx = blockIdx.x, tid = threadIdx.x;
    const __bf16* asrc = Sred + (size_t)bx * (64 * 192);
#pragma unroll
    for (int it = 0; it < 3; ++it) {
        int e = (it * 512 + tid) * 8;
        int r = e / 192, c = e - r * 192;
        *reinterpret_cast<bf16x8*>(&As[r][c]) =
            *reinterpret_cast<const bf16x8*>(asrc + e);
    }
    __syncthreads();

    int wv = tid >> 6, lane = tid & 63, quad = lane >> 4, l16 = lane & 15;
    bf16x8 af[4][6];
#pragma unroll
    for (int m = 0; m < 4; ++m)
#pragma unroll
        for (int kk = 0; kk < 6; ++kk)
            af[m][kk] = *reinterpret_cast<const bf16x8*>(
                &As[m * 16 + l16][kk * 32 + quad * 8]);

    float ps[4][4] = {{0.f,0.f,0.f,0.f},{0.f,0.f,0.f,0.f},
                      {0.f,0.f,0.f,0.f},{0.f,0.f,0.f,0.f}};
    for (int nt = 0; nt < 16; ++nt) {
        int n0 = wv * 256 + nt * 16;
        f32x4 acc[4];
#pragma unroll
        for (int m = 0; m < 4; ++m) acc[m] = (f32x4){0.f, 0.f, 0.f, 0.f};
        const __bf16* bp = fc2w_bf + (size_t)(n0 + l16) * 192 + quad * 8;
#pragma unroll
        for (int kk = 0; kk < 6; ++kk) {
            bf16x8 b = *reinterpret_cast<const bf16x8*>(bp + kk * 32);
#pragma unroll
            for (int m = 0; m < 4; ++m) acc[m] = MFMA16(af[m][kk], b, acc[m]);
        }
        int n = n0 + l16;
        float hh = h2[n], bb = bb2[n], ffv = f3[n];
#pragma unroll
        for (int m = 0; m < 4; ++m)
#pragma unroll
            for (int r = 0; r < 4; ++r)
                ps[m][r] += fmaxf(acc[m][r] * hh + bb, 0.f) * ffv;
    }
#pragma unroll
    for (int m = 0; m < 4; ++m)
#pragma unroll
        for (int r = 0; r < 4; ++r) {
            float v = ps[m][r];
            v += __shfl_xor(v, 1, 64);
            v += __shfl_xor(v, 2, 64);
            v += __shfl_xor(v, 4, 64);
            v += __shfl_xor(v, 8, 64);
            if (l16 == 0) psum_lds[wv][m * 16 + quad * 4 + r] = v;
        }
    __syncthreads();
    if (tid < 32) {
        float s = 0.f;
#pragma unroll
        for (int w = 0; w < 8; ++w)
            s += psum_lds[w][2 * tid] + psum_lds[w][2 * tid + 1];
        const float c1 = rsqrtf(1.f + 1e-5f);
        out[bx * 32 + tid] = (s + 2.f * fc3b[0]) * (bn3g[0] * c1) + bn3b[0];
    }
}

// ---------------------------------------------------------------------------
extern "C" void kernel_launch(void* const* d_in, const int* in_sizes, int n_in,
                              void* d_out, int out_size, void* d_ws, size_t ws_size,
                              hipStream_t stream)
{
    const float* q_feat = (const float*)d_in[0];
    const float* g_feat = (const float*)d_in[1];
    const float* se     = (const float*)d_in[2];
    const float* fc0w   = (const float*)d_in[3];
    const float* fc0b   = (const float*)d_in[4];
    const float* fc2w   = (const float*)d_in[5];
    const float* fc2b   = (const float*)d_in[6];
    const float* fc3w   = (const float*)d_in[7];
    const float* fc3b   = (const float*)d_in[8];
    const float* bn1g   = (const float*)d_in[9];
    const float* bn1b   = (const float*)d_in[10];
    const float* bn2g   = (const float*)d_in[11];
    const float* bn2b   = (const float*)d_in[12];
    const float* bn3g   = (const float*)d_in[13];
    const float* bn3b   = (const float*)d_in[14];
    float* out = (float*)d_out;

    char* ws = (char*)d_ws;
    __bf16* kfragA   = (__bf16*)(ws);                 //  6,291,456 B
    __bf16* qfrag16  = (__bf16*)(ws +  6291456);      //  3,145,728 B
    __bf16* sig16    = (__bf16*)(ws +  9437184);      //     73,728 B
    __bf16* fc2w_bf  = (__bf16*)(ws +  9543680);      //    786,432 B
    float*  h2       = (float*) (ws + 10330112);      //      8,192 B
    float*  bb2      = (float*) (ws + 10338304);      //      8,192 B
    float*  f3       = (float*) (ws + 10346496);      //      8,192 B
    __bf16* Sred     = (__bf16*)(ws + 10354688);      //  6,291,456 B (16.65 MB total)

    proj_prep_kernel<<<1312, 256, 0, stream>>>(q_feat, g_feat, fc0w, fc0b, se,
                                               fc2w, fc2b, bn2g, bn2b, fc3w,
                                               kfragA, qfrag16, sig16, fc2w_bf,
                                               h2, bb2, f3);
    score_kernel<<<1024, 256, 0, stream>>>(kfragA, qfrag16, sig16, bn1g, bn1b, Sred);
    mlp_kernel<<<256, 512, 0, stream>>>(Sred, fc2w_bf, h2, bb2, f3,
                                        fc3b, bn3g, bn3b, out);
}

// Round 9
// 229.644 us; speedup vs baseline: 2.3380x; 1.0882x over previous
//
#include <hip/hip_runtime.h>

// Shapes (fixed by the problem)
#define LL 192
#define FF 2048

typedef __attribute__((__ext_vector_type__(8)))  __bf16 bf16x8;
typedef __attribute__((__ext_vector_type__(4)))  __bf16 bf16x4;
typedef __attribute__((__ext_vector_type__(4)))  float  f32x4;

#define MFMA16(a, b, c) __builtin_amdgcn_mfma_f32_16x16x32_bf16((a), (b), (c), 0, 0, 0)

// Empirical gfx950 laws (R1-R8 evidence):
//  - VGPR budget ~= 256 / (launch_bounds 2nd arg), any block size.
//  - VGPR_Count == budget -> cap was HIT -> suspect scratch spill (R4/R7).
//  - 256-thr blocks co-schedule by LDS footprint (R4: 77.8KB -> 2/CU);
//    384-thr blocks don't co-schedule (R6).
//  - Stream-shared operands staged once per block in LDS; small invariant
//    operands hoisted in regs (Q-frags, 48 regs / 8 pairs).
//  - R8 pipe split @2 blocks/CU: VALU 45%, MFMA 22%, ~33% idle -> raise
//    blocks/CU by shrinking LDS (this round: 31KB -> 5 blocks).

// ---------------------------------------------------------------------------
// Kernel 1: fused projection + prep.
//   blocks 0..1151  : y = X @ fc0_w^T + fc0_b -> kfragA / qfrag16 (MFMA
//                     fragment order; fc0_w converted from f32 in-block).
//   blocks 1152..1311: sig16 (16x16 C-reg order), bf16 fc2_w, MLP constants.
// ---------------------------------------------------------------------------
__launch_bounds__(256, 2)
__global__ void proj_prep_kernel(const float* __restrict__ qf_in,
                                 const float* __restrict__ gf_in,
                                 const float* __restrict__ fc0w,
                                 const float* __restrict__ fc0b,
                                 const float* __restrict__ se,
                                 const float* __restrict__ fc2w,
                                 const float* __restrict__ fc2b,
                                 const float* __restrict__ bn2g,
                                 const float* __restrict__ bn2b,
                                 const float* __restrict__ fc3w,
                                 __bf16* __restrict__ kfragA,
                                 __bf16* __restrict__ qfrag16,
                                 __bf16* __restrict__ sig16,
                                 __bf16* __restrict__ fc2w_bf,
                                 float* __restrict__ h2,
                                 float* __restrict__ bb2,
                                 float* __restrict__ f3)
{
    int bx = blockIdx.x, tid = threadIdx.x;
    if (bx >= 1152) {
        int i0 = (bx - 1152) * 256 + tid;
        const int stride = 160 * 256;
        const float c1 = rsqrtf(1.f + 1e-5f);
        for (int i = i0; i < LL * LL; i += stride) {
            int r = i & 3, lane = (i >> 2) & 63, tile = i >> 8;
            int jt = tile % 12, st = tile / 12;
            int s = st * 16 + (lane >> 4) * 4 + r;
            int t = jt * 16 + (lane & 15);
            sig16[i] = (__bf16)(1.f / (1.f + __expf(-se[s * 192 + t])));
        }
        for (int i = i0; i < FF * LL; i += stride)
            fc2w_bf[i] = (__bf16)fc2w[i];
        for (int i = i0; i < FF; i += stride) {
            float h = bn2g[i] * c1;
            h2[i]  = h;
            bb2[i] = fc2b[i] * h + bn2b[i];
            f3[i]  = fc3w[i];
        }
        return;
    }
    __shared__ __bf16 Xs[32][136];
    __shared__ __bf16 Ws[128][136];
    __shared__ __bf16 Os[4096];          // 32 rows x 128, fragment order
    const float* src = (bx < 384) ? (qf_in + (size_t)bx * (32 * 128))
                                  : (gf_in + (size_t)(bx - 384) * (32 * 128));
#pragma unroll
    for (int it = 0; it < 4; ++it) {
        int e = (it * 256 + tid) * 4;
        int r = e >> 7, c = e & 127;
        float4 v = *reinterpret_cast<const float4*>(src + e);
        bf16x4 xv;
        xv[0] = (__bf16)v.x; xv[1] = (__bf16)v.y;
        xv[2] = (__bf16)v.z; xv[3] = (__bf16)v.w;
        *reinterpret_cast<bf16x4*>(&Xs[r][c]) = xv;
    }
#pragma unroll
    for (int it = 0; it < 16; ++it) {    // fc0_w f32 -> bf16 in LDS
        int e = (it * 256 + tid) * 4;
        int r = e >> 7, c = e & 127;
        float4 v = *reinterpret_cast<const float4*>(fc0w + e);
        bf16x4 xv;
        xv[0] = (__bf16)v.x; xv[1] = (__bf16)v.y;
        xv[2] = (__bf16)v.z; xv[3] = (__bf16)v.w;
        *reinterpret_cast<bf16x4*>(&Ws[r][c]) = xv;
    }
    __syncthreads();

    int wv = tid >> 6, lane = tid & 63, quad = lane >> 4, l16 = lane & 15;
    int n0 = wv * 32;
    f32x4 acc[2][2];
#pragma unroll
    for (int m = 0; m < 2; ++m)
#pragma unroll
        for (int n = 0; n < 2; ++n) acc[m][n] = (f32x4){0.f, 0.f, 0.f, 0.f};
#pragma unroll
    for (int ks = 0; ks < 4; ++ks) {
        bf16x8 a0 = *reinterpret_cast<const bf16x8*>(&Xs[l16][ks * 32 + quad * 8]);
        bf16x8 a1 = *reinterpret_cast<const bf16x8*>(&Xs[16 + l16][ks * 32 + quad * 8]);
        bf16x8 b0 = *reinterpret_cast<const bf16x8*>(&Ws[n0 + l16][ks * 32 + quad * 8]);
        bf16x8 b1 = *reinterpret_cast<const bf16x8*>(&Ws[n0 + 16 + l16][ks * 32 + quad * 8]);
        acc[0][0] = MFMA16(a0, b0, acc[0][0]);
        acc[0][1] = MFMA16(a0, b1, acc[0][1]);
        acc[1][0] = MFMA16(a1, b0, acc[1][0]);
        acc[1][1] = MFMA16(a1, b1, acc[1][1]);
    }
#pragma unroll
    for (int mt = 0; mt < 2; ++mt)
#pragma unroll
        for (int nt = 0; nt < 2; ++nt) {
            int d = n0 + nt * 16 + l16;
            float bv = fc0b[d];
            int abase = mt * 2048 + (d >> 5) * 512 + ((d >> 3) & 3) * 128 + (d & 7);
#pragma unroll
            for (int r = 0; r < 4; ++r)
                Os[abase + (quad * 4 + r) * 8] = (__bf16)(acc[mt][nt][r] + bv);
        }
    __syncthreads();

    int row0 = bx * 32;
    __bf16* dst;
    if (bx < 384) {
        int qi = row0 / 192, tg0 = (row0 % 192) >> 4;
        dst = qfrag16 + qi * 24576 + tg0 * 2048;
    } else {
        int rk0 = row0 - 12288;
        int ki = rk0 / 192, sg0 = (rk0 % 192) >> 4;
        dst = kfragA + ki * 24576 + sg0 * 2048;
    }
#pragma unroll
    for (int it = 0; it < 2; ++it) {
        int e = (it * 256 + tid) * 8;
        *reinterpret_cast<bf16x8*>(dst + e) =
            *reinterpret_cast<const bf16x8*>(&Os[e]);
    }
}

// ---------------------------------------------------------------------------
// Kernel 2: per-pair score GEMM + sigmoid-modulation + dual max-reduce.
//    256 threads = 4 waves.  Wave w owns fixed t-slice {3w..3w+2} (48 cols):
//      - B (query) fragments hoisted in regs once per block (48 VGPRs / 8 pairs)
//      - A (key) staged per pair in TWO 24KB HALVES (96 s-rows each) ->
//        LDS 31KB total -> 5 blocks/CU (20 waves) for pipe overlap
//      - sig streamed from L2 in C-register order (disjoint per wave)
//    Row-max: 2 DPP shuffles + 4-class LDS scatter + combine.
//    Col-max: in-register across both halves, 2 shuffles, direct write.
//    ~90 VGPRs (budget 128 via (256,2)) -> no spill.
// ---------------------------------------------------------------------------
__launch_bounds__(256, 2)
__global__ void score_kernel(const __bf16* __restrict__ kfragA,
                             const __bf16* __restrict__ qfrag16,
                             const __bf16* __restrict__ sig16,
                             const float* __restrict__ bn1g,
                             const float* __restrict__ bn1b,
                             __bf16* __restrict__ Sred)
{
    __shared__ __bf16 Abuf[12288];      // 24,576 B: K fragments, half-pair
    __shared__ __bf16 rowT4[16][200];   //  6,400 B: row-max partials

    int tid = threadIdx.x;
    int q = blockIdx.x & 63;
    int kbase = (blockIdx.x >> 6) << 3;    // kg-major: kfragA L2 locality
    int w = tid >> 6, lane = tid & 63, quad = lane >> 4, l16 = lane & 15;
    const float g1c = bn1g[0] * rsqrtf(1.f + 1e-5f);
    const float b1v = bn1b[0];

    // Hoist B (query) fragments for this wave's t-slice: 12 x bf16x8 = 48 VGPR
    bf16x8 Bf[3][4];
    {
        const __bf16* qb = qfrag16 + (size_t)q * 24576 + lane * 8;
#pragma unroll
        for (int j = 0; j < 3; ++j)
#pragma unroll
            for (int ks = 0; ks < 4; ++ks)
                Bf[j][ks] = *reinterpret_cast<const bf16x8*>(
                    qb + ((3 * w + j) * 4 + ks) * 512);
    }

#pragma unroll 1
    for (int kk = 0; kk < 8; ++kk) {
        int kidx = kbase + kk;
        const __bf16* kp = kfragA + (size_t)kidx * 24576;
        size_t ob = (size_t)(q * 128 + kidx) * 384;
        float cm0 = -3.0e38f, cm1 = -3.0e38f, cm2 = -3.0e38f;

#pragma unroll 1
        for (int h = 0; h < 2; ++h) {
            // stage half h: s-rows [96h, 96h+96)
#pragma unroll
            for (int it = 0; it < 6; ++it) {
                int e = (it * 256 + tid) * 8;
                *reinterpret_cast<bf16x8*>(&Abuf[e]) =
                    *reinterpret_cast<const bf16x8*>(kp + 12288 * h + e);
            }
            __syncthreads();   // Abuf ready (and prev-half reads done)

#pragma unroll 1
            for (int lsc = 0; lsc < 3; ++lsc) {   // 32 s-rows per chunk
                f32x4 acc[2][3];
#pragma unroll
                for (int i = 0; i < 2; ++i)
#pragma unroll
                    for (int j = 0; j < 3; ++j)
                        acc[i][j] = (f32x4){0.f, 0.f, 0.f, 0.f};

#pragma unroll
                for (int ks = 0; ks < 4; ++ks) {
                    bf16x8 a0 = *reinterpret_cast<const bf16x8*>(
                        &Abuf[((lsc * 2 + 0) * 4 + ks) * 512 + lane * 8]);
                    bf16x8 a1 = *reinterpret_cast<const bf16x8*>(
                        &Abuf[((lsc * 2 + 1) * 4 + ks) * 512 + lane * 8]);
#pragma unroll
                    for (int j = 0; j < 3; ++j) {
                        acc[0][j] = MFMA16(a0, Bf[j][ks], acc[0][j]);
                        acc[1][j] = MFMA16(a1, Bf[j][ks], acc[1][j]);
                    }
                }

                // epilogue: v = acc * sig
                //   s = 96h + lsc*32 + 16i + quad*4 + r,  t = (3w+j)*16 + l16
#pragma unroll
                for (int i = 0; i < 2; ++i) {
                    int stile = 6 * h + lsc * 2 + i;
                    float rm0 = -3.0e38f, rm1 = -3.0e38f, rm2 = -3.0e38f, rm3 = -3.0e38f;
#pragma unroll
                    for (int j = 0; j < 3; ++j) {
                        bf16x4 sv = *reinterpret_cast<const bf16x4*>(
                            sig16 + ((size_t)(stile * 12 + 3 * w + j) * 64
                                     + lane) * 4);
                        float v0 = acc[i][j][0] * (float)sv[0];
                        float v1 = acc[i][j][1] * (float)sv[1];
                        float v2 = acc[i][j][2] * (float)sv[2];
                        float v3 = acc[i][j][3] * (float)sv[3];
                        rm0 = fmaxf(rm0, v0); rm1 = fmaxf(rm1, v1);
                        rm2 = fmaxf(rm2, v2); rm3 = fmaxf(rm3, v3);
                        float cj = fmaxf(fmaxf(v0, v1), fmaxf(v2, v3));
                        if (j == 0) cm0 = fmaxf(cm0, cj);
                        else if (j == 1) cm1 = fmaxf(cm1, cj);
                        else cm2 = fmaxf(cm2, cj);
                    }
                    // reduce over l16 bits 0,1 (quad_perm DPP)
                    rm0 = fmaxf(rm0, __shfl_xor(rm0, 1, 64));
                    rm0 = fmaxf(rm0, __shfl_xor(rm0, 2, 64));
                    rm1 = fmaxf(rm1, __shfl_xor(rm1, 1, 64));
                    rm1 = fmaxf(rm1, __shfl_xor(rm1, 2, 64));
                    rm2 = fmaxf(rm2, __shfl_xor(rm2, 1, 64));
                    rm2 = fmaxf(rm2, __shfl_xor(rm2, 2, 64));
                    rm3 = fmaxf(rm3, __shfl_xor(rm3, 1, 64));
                    rm3 = fmaxf(rm3, __shfl_xor(rm3, 2, 64));
                    if ((l16 & 3) == 0) {
                        bf16x4 pk;
                        pk[0] = (__bf16)rm0; pk[1] = (__bf16)rm1;
                        pk[2] = (__bf16)rm2; pk[3] = (__bf16)rm3;
                        *reinterpret_cast<bf16x4*>(
                            &rowT4[(l16 >> 2) * 4 + w]
                                  [96 * h + lsc * 32 + 16 * i + quad * 4]) = pk;
                    }
                }
            }
            __syncthreads();   // half consumed; (h=1): rowT4 fully written
        }

        // col-max (max over s, indexed by t): reduce over quad, direct write
        {
            float v0 = cm0, v1 = cm1, v2 = cm2;
            v0 = fmaxf(v0, __shfl_xor(v0, 16, 64));
            v0 = fmaxf(v0, __shfl_xor(v0, 32, 64));
            v1 = fmaxf(v1, __shfl_xor(v1, 16, 64));
            v1 = fmaxf(v1, __shfl_xor(v1, 32, 64));
            v2 = fmaxf(v2, __shfl_xor(v2, 16, 64));
            v2 = fmaxf(v2, __shfl_xor(v2, 32, 64));
            if (quad == 0) {
                Sred[ob + (3 * w + 0) * 16 + l16] = (__bf16)(v0 * g1c + b1v);
                Sred[ob + (3 * w + 1) * 16 + l16] = (__bf16)(v1 * g1c + b1v);
                Sred[ob + (3 * w + 2) * 16 + l16] = (__bf16)(v2 * g1c + b1v);
            }
        }

        // row-max combine (max over t, indexed by s); rowT4 complete per the
        // barrier ending h=1.  Next pair's rowT4 writes happen only after the
        // next staging barrier -> no WAR hazard on these reads.
        if (tid < 192) {
            float m1 = -3.0e38f;
#pragma unroll
            for (int c = 0; c < 16; ++c)
                m1 = fmaxf(m1, (float)rowT4[c][tid]);
            Sred[ob + 192 + tid] = (__bf16)(m1 * g1c + b1v);
        }
    }
}

// ---------------------------------------------------------------------------
// Kernel 3: fused fc2 + bn2 + relu + fc3 + pair-sum + bn3.  64 Sred rows per
//    block, 8 waves x 256 ff-cols.  grid 256 = 1 block/CU, (512,1) -> full
//    256-reg budget, af[4][6]=96 regs hoisted, no spill.
// ---------------------------------------------------------------------------
__launch_bounds__(512, 1)
__global__ void mlp_kernel(const __bf16* __restrict__ Sred,
                           const __bf16* __restrict__ fc2w_bf,
                           const float* __restrict__ h2,
                           const float* __restrict__ bb2,
                           const float* __restrict__ f3,
                           const float* __restrict__ fc3b,
                           const float* __restrict__ bn3g,
                           const float* __restrict__ bn3b,
                           float* __restrict__ out)
{
    __shared__ __bf16 As[64][200];
    __shared__ float  psum_lds[8][64];
    int bx = blockIdx.x, tid = threadIdx.x;
    const __bf16* asrc = Sred + (size_t)bx * (64 * 192);
#pragma unroll
    for (int it = 0; it < 3; ++it) {
        int e = (it * 512 + tid) * 8;
        int r = e / 192, c = e - r * 192;
        *reinterpret_cast<bf16x8*>(&As[r][c]) =
            *reinterpret_cast<const bf16x8*>(asrc + e);
    }
    __syncthreads();

    int wv = tid >> 6, lane = tid & 63, quad = lane >> 4, l16 = lane & 15;
    bf16x8 af[4][6];
#pragma unroll
    for (int m = 0; m < 4; ++m)
#pragma unroll
        for (int kk = 0; kk < 6; ++kk)
            af[m][kk] = *reinterpret_cast<const bf16x8*>(
                &As[m * 16 + l16][kk * 32 + quad * 8]);

    float ps[4][4] = {{0.f,0.f,0.f,0.f},{0.f,0.f,0.f,0.f},
                      {0.f,0.f,0.f,0.f},{0.f,0.f,0.f,0.f}};
    for (int nt = 0; nt < 16; ++nt) {
        int n0 = wv * 256 + nt * 16;
        f32x4 acc[4];
#pragma unroll
        for (int m = 0; m < 4; ++m) acc[m] = (f32x4){0.f, 0.f, 0.f, 0.f};
        const __bf16* bp = fc2w_bf + (size_t)(n0 + l16) * 192 + quad * 8;
#pragma unroll
        for (int kk = 0; kk < 6; ++kk) {
            bf16x8 b = *reinterpret_cast<const bf16x8*>(bp + kk * 32);
#pragma unroll
            for (int m = 0; m < 4; ++m) acc[m] = MFMA16(af[m][kk], b, acc[m]);
        }
        int n = n0 + l16;
        float hh = h2[n], bb = bb2[n], ffv = f3[n];
#pragma unroll
        for (int m = 0; m < 4; ++m)
#pragma unroll
            for (int r = 0; r < 4; ++r)
                ps[m][r] += fmaxf(acc[m][r] * hh + bb, 0.f) * ffv;
    }
#pragma unroll
    for (int m = 0; m < 4; ++m)
#pragma unroll
        for (int r = 0; r < 4; ++r) {
            float v = ps[m][r];
            v += __shfl_xor(v, 1, 64);
            v += __shfl_xor(v, 2, 64);
            v += __shfl_xor(v, 4, 64);
            v += __shfl_xor(v, 8, 64);
            if (l16 == 0) psum_lds[wv][m * 16 + quad * 4 + r] = v;
        }
    __syncthreads();
    if (tid < 32) {
        float s = 0.f;
#pragma unroll
        for (int w = 0; w < 8; ++w)
            s += psum_lds[w][2 * tid] + psum_lds[w][2 * tid + 1];
        const float c1 = rsqrtf(1.f + 1e-5f);
        out[bx * 32 + tid] = (s + 2.f * fc3b[0]) * (bn3g[0] * c1) + bn3b[0];
    }
}

// ---------------------------------------------------------------------------
extern "C" void kernel_launch(void* const* d_in, const int* in_sizes, int n_in,
                              void* d_out, int out_size, void* d_ws, size_t ws_size,
                              hipStream_t stream)
{
    const float* q_feat = (const float*)d_in[0];
    const float* g_feat = (const float*)d_in[1];
    const float* se     = (const float*)d_in[2];
    const float* fc0w   = (const float*)d_in[3];
    const float* fc0b   = (const float*)d_in[4];
    const float* fc2w   = (const float*)d_in[5];
    const float* fc2b   = (const float*)d_in[6];
    const float* fc3w   = (const float*)d_in[7];
    const float* fc3b   = (const float*)d_in[8];
    const float* bn1g   = (const float*)d_in[9];
    const float* bn1b   = (const float*)d_in[10];
    const float* bn2g   = (const float*)d_in[11];
    const float* bn2b   = (const float*)d_in[12];
    const float* bn3g   = (const float*)d_in[13];
    const float* bn3b   = (const float*)d_in[14];
    float* out = (float*)d_out;

    char* ws = (char*)d_ws;
    __bf16* kfragA   = (__bf16*)(ws);                 //  6,291,456 B
    __bf16* qfrag16  = (__bf16*)(ws +  6291456);      //  3,145,728 B
    __bf16* sig16    = (__bf16*)(ws +  9437184);      //     73,728 B
    __bf16* fc2w_bf  = (__bf16*)(ws +  9543680);      //    786,432 B
    float*  h2       = (float*) (ws + 10330112);      //      8,192 B
    float*  bb2      = (float*) (ws + 10338304);      //      8,192 B
    float*  f3       = (float*) (ws + 10346496);      //      8,192 B
    __bf16* Sred     = (__bf16*)(ws + 10354688);      //  6,291,456 B (16.65 MB total)

    proj_prep_kernel<<<1312, 256, 0, stream>>>(q_feat, g_feat, fc0w, fc0b, se,
                                               fc2w, fc2b, bn2g, bn2b, fc3w,
                                               kfragA, qfrag16, sig16, fc2w_bf,
                                               h2, bb2, f3);
    score_kernel<<<1024, 256, 0, stream>>>(kfragA, qfrag16, sig16, bn1g, bn1b, Sred);
    mlp_kernel<<<256, 512, 0, stream>>>(Sred, fc2w_bf, h2, bb2, f3,
                                        fc3b, bn3g, bn3b, out);
}

// Round 10
// 228.932 us; speedup vs baseline: 2.3453x; 1.0031x over previous
//
#include <hip/hip_runtime.h>

// Shapes (fixed by the problem)
#define LL 192
#define FF 2048

typedef __attribute__((__ext_vector_type__(8)))  __bf16 bf16x8;
typedef __attribute__((__ext_vector_type__(4)))  __bf16 bf16x4;
typedef __attribute__((__ext_vector_type__(4)))  float  f32x4;

#define MFMA16(a, b, c) __builtin_amdgcn_mfma_f32_16x16x32_bf16((a), (b), (c), 0, 0, 0)

// Empirical gfx950 laws (R1-R9 evidence):
//  - VGPR budget ~= 256 / (launch_bounds 2nd arg); VGPR_Count==budget -> spill.
//  - 256-thr blocks co-schedule by LDS footprint; 384-thr blocks don't (R6).
//  - Grid must exceed (resident blocks/CU)*256 or occupancy is grid-capped
//    (R9: grid 1024 = 4/CU capped average occupancy at 36%).
//  - Stream-shared operands staged per block in LDS; invariant operands in regs.
//  - R9 pipe split: VALU 57% > MFMA 28% -> cut epilogue VALU (f32 sig, max3)
//    and raise blocks/CU (22.8KB LDS -> 7/CU).

// ---------------------------------------------------------------------------
// Kernel 1: fused projection + prep.
//   blocks 0..1151  : y = X @ fc0_w^T + fc0_b -> kfragA / qfrag16 (MFMA
//                     fragment order; fc0_w converted from f32 in-block).
//   blocks 1152..1311: sig32 (f32, 16x16 C-reg order), bf16 fc2_w, MLP consts.
// ---------------------------------------------------------------------------
__launch_bounds__(256, 2)
__global__ void proj_prep_kernel(const float* __restrict__ qf_in,
                                 const float* __restrict__ gf_in,
                                 const float* __restrict__ fc0w,
                                 const float* __restrict__ fc0b,
                                 const float* __restrict__ se,
                                 const float* __restrict__ fc2w,
                                 const float* __restrict__ fc2b,
                                 const float* __restrict__ bn2g,
                                 const float* __restrict__ bn2b,
                                 const float* __restrict__ fc3w,
                                 __bf16* __restrict__ kfragA,
                                 __bf16* __restrict__ qfrag16,
                                 float* __restrict__ sig32,
                                 __bf16* __restrict__ fc2w_bf,
                                 float* __restrict__ h2,
                                 float* __restrict__ bb2,
                                 float* __restrict__ f3)
{
    int bx = blockIdx.x, tid = threadIdx.x;
    if (bx >= 1152) {
        int i0 = (bx - 1152) * 256 + tid;
        const int stride = 160 * 256;
        const float c1 = rsqrtf(1.f + 1e-5f);
        for (int i = i0; i < LL * LL; i += stride) {
            int r = i & 3, lane = (i >> 2) & 63, tile = i >> 8;
            int jt = tile % 12, st = tile / 12;
            int s = st * 16 + (lane >> 4) * 4 + r;
            int t = jt * 16 + (lane & 15);
            sig32[i] = 1.f / (1.f + __expf(-se[s * 192 + t]));
        }
        for (int i = i0; i < FF * LL; i += stride)
            fc2w_bf[i] = (__bf16)fc2w[i];
        for (int i = i0; i < FF; i += stride) {
            float h = bn2g[i] * c1;
            h2[i]  = h;
            bb2[i] = fc2b[i] * h + bn2b[i];
            f3[i]  = fc3w[i];
        }
        return;
    }
    __shared__ __bf16 Xs[32][136];
    __shared__ __bf16 Ws[128][136];
    __shared__ __bf16 Os[4096];          // 32 rows x 128, fragment order
    const float* src = (bx < 384) ? (qf_in + (size_t)bx * (32 * 128))
                                  : (gf_in + (size_t)(bx - 384) * (32 * 128));
#pragma unroll
    for (int it = 0; it < 4; ++it) {
        int e = (it * 256 + tid) * 4;
        int r = e >> 7, c = e & 127;
        float4 v = *reinterpret_cast<const float4*>(src + e);
        bf16x4 xv;
        xv[0] = (__bf16)v.x; xv[1] = (__bf16)v.y;
        xv[2] = (__bf16)v.z; xv[3] = (__bf16)v.w;
        *reinterpret_cast<bf16x4*>(&Xs[r][c]) = xv;
    }
#pragma unroll
    for (int it = 0; it < 16; ++it) {    // fc0_w f32 -> bf16 in LDS
        int e = (it * 256 + tid) * 4;
        int r = e >> 7, c = e & 127;
        float4 v = *reinterpret_cast<const float4*>(fc0w + e);
        bf16x4 xv;
        xv[0] = (__bf16)v.x; xv[1] = (__bf16)v.y;
        xv[2] = (__bf16)v.z; xv[3] = (__bf16)v.w;
        *reinterpret_cast<bf16x4*>(&Ws[r][c]) = xv;
    }
    __syncthreads();

    int wv = tid >> 6, lane = tid & 63, quad = lane >> 4, l16 = lane & 15;
    int n0 = wv * 32;
    f32x4 acc[2][2];
#pragma unroll
    for (int m = 0; m < 2; ++m)
#pragma unroll
        for (int n = 0; n < 2; ++n) acc[m][n] = (f32x4){0.f, 0.f, 0.f, 0.f};
#pragma unroll
    for (int ks = 0; ks < 4; ++ks) {
        bf16x8 a0 = *reinterpret_cast<const bf16x8*>(&Xs[l16][ks * 32 + quad * 8]);
        bf16x8 a1 = *reinterpret_cast<const bf16x8*>(&Xs[16 + l16][ks * 32 + quad * 8]);
        bf16x8 b0 = *reinterpret_cast<const bf16x8*>(&Ws[n0 + l16][ks * 32 + quad * 8]);
        bf16x8 b1 = *reinterpret_cast<const bf16x8*>(&Ws[n0 + 16 + l16][ks * 32 + quad * 8]);
        acc[0][0] = MFMA16(a0, b0, acc[0][0]);
        acc[0][1] = MFMA16(a0, b1, acc[0][1]);
        acc[1][0] = MFMA16(a1, b0, acc[1][0]);
        acc[1][1] = MFMA16(a1, b1, acc[1][1]);
    }
#pragma unroll
    for (int mt = 0; mt < 2; ++mt)
#pragma unroll
        for (int nt = 0; nt < 2; ++nt) {
            int d = n0 + nt * 16 + l16;
            float bv = fc0b[d];
            int abase = mt * 2048 + (d >> 5) * 512 + ((d >> 3) & 3) * 128 + (d & 7);
#pragma unroll
            for (int r = 0; r < 4; ++r)
                Os[abase + (quad * 4 + r) * 8] = (__bf16)(acc[mt][nt][r] + bv);
        }
    __syncthreads();

    int row0 = bx * 32;
    __bf16* dst;
    if (bx < 384) {
        int qi = row0 / 192, tg0 = (row0 % 192) >> 4;
        dst = qfrag16 + qi * 24576 + tg0 * 2048;
    } else {
        int rk0 = row0 - 12288;
        int ki = rk0 / 192, sg0 = (rk0 % 192) >> 4;
        dst = kfragA + ki * 24576 + sg0 * 2048;
    }
#pragma unroll
    for (int it = 0; it < 2; ++it) {
        int e = (it * 256 + tid) * 8;
        *reinterpret_cast<bf16x8*>(dst + e) =
            *reinterpret_cast<const bf16x8*>(&Os[e]);
    }
}

// ---------------------------------------------------------------------------
// Kernel 2: per-pair score GEMM + sigmoid-modulation + dual max-reduce.
//    Grid 2048 x 4 pairs (q = bx&63, kgroup = bx>>6).  256 threads = 4 waves,
//    wave w owns fixed t-slice {3w..3w+2}:
//      - B (query) frags hoisted in regs once per block (48 VGPRs / 4 pairs)
//      - A (key) staged per pair in THREE 16.4KB thirds (64 s-rows each) ->
//        LDS 22.8KB -> 7 blocks/CU resident (grid 8/CU keeps them fed)
//      - sig32 (f32) streamed from L2 in C-reg order: no cvt, mul directly
//    Row-max: v_max3 over j + 2 DPP shuffles + 4-class LDS scatter + combine.
//    Col-max: in-register, 2 shuffles, direct write.
// ---------------------------------------------------------------------------
__launch_bounds__(256, 2)
__global__ void score_kernel(const __bf16* __restrict__ kfragA,
                             const __bf16* __restrict__ qfrag16,
                             const float* __restrict__ sig32,
                             const float* __restrict__ bn1g,
                             const float* __restrict__ bn1b,
                             __bf16* __restrict__ Sred)
{
    __shared__ __bf16 Abuf[8192];       // 16,384 B: 64 s-rows of K frags
    __shared__ __bf16 rowT4[16][200];   //  6,400 B: row-max partials

    int tid = threadIdx.x;
    int q = blockIdx.x & 63;
    int kbase = (blockIdx.x >> 6) << 2;    // 32 k-groups of 4 pairs
    int w = tid >> 6, lane = tid & 63, quad = lane >> 4, l16 = lane & 15;
    const float g1c = bn1g[0] * rsqrtf(1.f + 1e-5f);
    const float b1v = bn1b[0];

    // Hoist B (query) fragments for this wave's t-slice: 12 x bf16x8 = 48 VGPR
    bf16x8 Bf[3][4];
    {
        const __bf16* qb = qfrag16 + (size_t)q * 24576 + lane * 8;
#pragma unroll
        for (int j = 0; j < 3; ++j)
#pragma unroll
            for (int ks = 0; ks < 4; ++ks)
                Bf[j][ks] = *reinterpret_cast<const bf16x8*>(
                    qb + ((3 * w + j) * 4 + ks) * 512);
    }

#pragma unroll 1
    for (int kk = 0; kk < 4; ++kk) {
        int kidx = kbase + kk;
        const __bf16* kp = kfragA + (size_t)kidx * 24576;
        size_t ob = (size_t)(q * 128 + kidx) * 384;
        float cm0 = -3.0e38f, cm1 = -3.0e38f, cm2 = -3.0e38f;

#pragma unroll 1
        for (int h = 0; h < 3; ++h) {
            // stage third h: s-rows [64h, 64h+64) = 8192 bf16
#pragma unroll
            for (int it = 0; it < 4; ++it) {
                int e = (it * 256 + tid) * 8;
                *reinterpret_cast<bf16x8*>(&Abuf[e]) =
                    *reinterpret_cast<const bf16x8*>(kp + 8192 * h + e);
            }
            __syncthreads();   // Abuf ready (and prev-third reads done)

#pragma unroll 1
            for (int lsc = 0; lsc < 2; ++lsc) {   // 32 s-rows per chunk
                f32x4 acc[2][3];
#pragma unroll
                for (int i = 0; i < 2; ++i)
#pragma unroll
                    for (int j = 0; j < 3; ++j)
                        acc[i][j] = (f32x4){0.f, 0.f, 0.f, 0.f};

#pragma unroll
                for (int ks = 0; ks < 4; ++ks) {
                    bf16x8 a0 = *reinterpret_cast<const bf16x8*>(
                        &Abuf[((lsc * 2 + 0) * 4 + ks) * 512 + lane * 8]);
                    bf16x8 a1 = *reinterpret_cast<const bf16x8*>(
                        &Abuf[((lsc * 2 + 1) * 4 + ks) * 512 + lane * 8]);
#pragma unroll
                    for (int j = 0; j < 3; ++j) {
                        acc[0][j] = MFMA16(a0, Bf[j][ks], acc[0][j]);
                        acc[1][j] = MFMA16(a1, Bf[j][ks], acc[1][j]);
                    }
                }

                // epilogue: v = acc * sig (f32, no cvt)
                //   s = 64h + lsc*32 + 16i + quad*4 + r,  t = (3w+j)*16 + l16
#pragma unroll
                for (int i = 0; i < 2; ++i) {
                    int stile = 4 * h + lsc * 2 + i;
                    const float* sp = sig32 +
                        ((size_t)(stile * 12 + 3 * w) * 64 + lane) * 4;
                    f32x4 s0 = *reinterpret_cast<const f32x4*>(sp);
                    f32x4 s1 = *reinterpret_cast<const f32x4*>(sp + 256);
                    f32x4 s2 = *reinterpret_cast<const f32x4*>(sp + 512);
                    float v00 = acc[i][0][0] * s0[0], v01 = acc[i][0][1] * s0[1];
                    float v02 = acc[i][0][2] * s0[2], v03 = acc[i][0][3] * s0[3];
                    float v10 = acc[i][1][0] * s1[0], v11 = acc[i][1][1] * s1[1];
                    float v12 = acc[i][1][2] * s1[2], v13 = acc[i][1][3] * s1[3];
                    float v20 = acc[i][2][0] * s2[0], v21 = acc[i][2][1] * s2[1];
                    float v22 = acc[i][2][2] * s2[2], v23 = acc[i][2][3] * s2[3];
                    // row maxes over j: single v_max3 per r
                    float rm0 = fmaxf(fmaxf(v00, v10), v20);
                    float rm1 = fmaxf(fmaxf(v01, v11), v21);
                    float rm2 = fmaxf(fmaxf(v02, v12), v22);
                    float rm3 = fmaxf(fmaxf(v03, v13), v23);
                    // col maxes over r (max3 + max), folded into running cm
                    cm0 = fmaxf(cm0, fmaxf(fmaxf(fmaxf(v00, v01), v02), v03));
                    cm1 = fmaxf(cm1, fmaxf(fmaxf(fmaxf(v10, v11), v12), v13));
                    cm2 = fmaxf(cm2, fmaxf(fmaxf(fmaxf(v20, v21), v22), v23));
                    // reduce rm over l16 bits 0,1 (quad_perm DPP)
                    rm0 = fmaxf(rm0, __shfl_xor(rm0, 1, 64));
                    rm0 = fmaxf(rm0, __shfl_xor(rm0, 2, 64));
                    rm1 = fmaxf(rm1, __shfl_xor(rm1, 1, 64));
                    rm1 = fmaxf(rm1, __shfl_xor(rm1, 2, 64));
                    rm2 = fmaxf(rm2, __shfl_xor(rm2, 1, 64));
                    rm2 = fmaxf(rm2, __shfl_xor(rm2, 2, 64));
                    rm3 = fmaxf(rm3, __shfl_xor(rm3, 1, 64));
                    rm3 = fmaxf(rm3, __shfl_xor(rm3, 2, 64));
                    if ((l16 & 3) == 0) {
                        bf16x4 pk;
                        pk[0] = (__bf16)rm0; pk[1] = (__bf16)rm1;
                        pk[2] = (__bf16)rm2; pk[3] = (__bf16)rm3;
                        *reinterpret_cast<bf16x4*>(
                            &rowT4[(l16 >> 2) * 4 + w]
                                  [stile * 16 + quad * 4]) = pk;
                    }
                }
            }
            __syncthreads();   // third consumed; (h=2): rowT4 fully written
        }

        // col-max (max over s, indexed by t): reduce over quad, direct write
        {
            float v0 = cm0, v1 = cm1, v2 = cm2;
            v0 = fmaxf(v0, __shfl_xor(v0, 16, 64));
            v0 = fmaxf(v0, __shfl_xor(v0, 32, 64));
            v1 = fmaxf(v1, __shfl_xor(v1, 16, 64));
            v1 = fmaxf(v1, __shfl_xor(v1, 32, 64));
            v2 = fmaxf(v2, __shfl_xor(v2, 16, 64));
            v2 = fmaxf(v2, __shfl_xor(v2, 32, 64));
            if (quad == 0) {
                Sred[ob + (3 * w + 0) * 16 + l16] = (__bf16)(v0 * g1c + b1v);
                Sred[ob + (3 * w + 1) * 16 + l16] = (__bf16)(v1 * g1c + b1v);
                Sred[ob + (3 * w + 2) * 16 + l16] = (__bf16)(v2 * g1c + b1v);
            }
        }

        // row-max combine (max over t, indexed by s); rowT4 complete per the
        // barrier ending h=2; next pair's writes are fenced by its staging
        // barrier -> no WAR hazard.
        if (tid < 192) {
            float m1 = -3.0e38f;
#pragma unroll
            for (int c = 0; c < 16; ++c)
                m1 = fmaxf(m1, (float)rowT4[c][tid]);
            Sred[ob + 192 + tid] = (__bf16)(m1 * g1c + b1v);
        }
    }
}

// ---------------------------------------------------------------------------
// Kernel 3: fused fc2 + bn2 + relu + fc3 + pair-sum + bn3.  64 Sred rows per
//    block, 8 waves x 256 ff-cols.  grid 256 = 1 block/CU, (512,1) -> full
//    256-reg budget, af[4][6]=96 regs hoisted, no spill.
// ---------------------------------------------------------------------------
__launch_bounds__(512, 1)
__global__ void mlp_kernel(const __bf16* __restrict__ Sred,
                           const __bf16* __restrict__ fc2w_bf,
                           const float* __restrict__ h2,
                           const float* __restrict__ bb2,
                           const float* __restrict__ f3,
                           const float* __restrict__ fc3b,
                           const float* __restrict__ bn3g,
                           const float* __restrict__ bn3b,
                           float* __restrict__ out)
{
    __shared__ __bf16 As[64][200];
    __shared__ float  psum_lds[8][64];
    int bx = blockIdx.x, tid = threadIdx.x;
    const __bf16* asrc = Sred + (size_t)bx * (64 * 192);
#pragma unroll
    for (int it = 0; it < 3; ++it) {
        int e = (it * 512 + tid) * 8;
        int r = e / 192, c = e - r * 192;
        *reinterpret_cast<bf16x8*>(&As[r][c]) =
            *reinterpret_cast<const bf16x8*>(asrc + e);
    }
    __syncthreads();

    int wv = tid >> 6, lane = tid & 63, quad = lane >> 4, l16 = lane & 15;
    bf16x8 af[4][6];
#pragma unroll
    for (int m = 0; m < 4; ++m)
#pragma unroll
        for (int kk = 0; kk < 6; ++kk)
            af[m][kk] = *reinterpret_cast<const bf16x8*>(
                &As[m * 16 + l16][kk * 32 + quad * 8]);

    float ps[4][4] = {{0.f,0.f,0.f,0.f},{0.f,0.f,0.f,0.f},
                      {0.f,0.f,0.f,0.f},{0.f,0.f,0.f,0.f}};
    for (int nt = 0; nt < 16; ++nt) {
        int n0 = wv * 256 + nt * 16;
        f32x4 acc[4];
#pragma unroll
        for (int m = 0; m < 4; ++m) acc[m] = (f32x4){0.f, 0.f, 0.f, 0.f};
        const __bf16* bp = fc2w_bf + (size_t)(n0 + l16) * 192 + quad * 8;
#pragma unroll
        for (int kk = 0; kk < 6; ++kk) {
            bf16x8 b = *reinterpret_cast<const bf16x8*>(bp + kk * 32);
#pragma unroll
            for (int m = 0; m < 4; ++m) acc[m] = MFMA16(af[m][kk], b, acc[m]);
        }
        int n = n0 + l16;
        float hh = h2[n], bb = bb2[n], ffv = f3[n];
#pragma unroll
        for (int m = 0; m < 4; ++m)
#pragma unroll
            for (int r = 0; r < 4; ++r)
                ps[m][r] += fmaxf(acc[m][r] * hh + bb, 0.f) * ffv;
    }
#pragma unroll
    for (int m = 0; m < 4; ++m)
#pragma unroll
        for (int r = 0; r < 4; ++r) {
            float v = ps[m][r];
            v += __shfl_xor(v, 1, 64);
            v += __shfl_xor(v, 2, 64);
            v += __shfl_xor(v, 4, 64);
            v += __shfl_xor(v, 8, 64);
            if (l16 == 0) psum_lds[wv][m * 16 + quad * 4 + r] = v;
        }
    __syncthreads();
    if (tid < 32) {
        float s = 0.f;
#pragma unroll
        for (int w = 0; w < 8; ++w)
            s += psum_lds[w][2 * tid] + psum_lds[w][2 * tid + 1];
        const float c1 = rsqrtf(1.f + 1e-5f);
        out[bx * 32 + tid] = (s + 2.f * fc3b[0]) * (bn3g[0] * c1) + bn3b[0];
    }
}

// ---------------------------------------------------------------------------
extern "C" void kernel_launch(void* const* d_in, const int* in_sizes, int n_in,
                              void* d_out, int out_size, void* d_ws, size_t ws_size,
                              hipStream_t stream)
{
    const float* q_feat = (const float*)d_in[0];
    const float* g_feat = (const float*)d_in[1];
    const float* se     = (const float*)d_in[2];
    const float* fc0w   = (const float*)d_in[3];
    const float* fc0b   = (const float*)d_in[4];
    const float* fc2w   = (const float*)d_in[5];
    const float* fc2b   = (const float*)d_in[6];
    const float* fc3w   = (const float*)d_in[7];
    const float* fc3b   = (const float*)d_in[8];
    const float* bn1g   = (const float*)d_in[9];
    const float* bn1b   = (const float*)d_in[10];
    const float* bn2g   = (const float*)d_in[11];
    const float* bn2b   = (const float*)d_in[12];
    const float* bn3g   = (const float*)d_in[13];
    const float* bn3b   = (const float*)d_in[14];
    float* out = (float*)d_out;

    char* ws = (char*)d_ws;
    __bf16* kfragA   = (__bf16*)(ws);                 //  6,291,456 B
    __bf16* qfrag16  = (__bf16*)(ws +  6291456);      //  3,145,728 B
    float*  sig32    = (float*) (ws +  9437184);      //    147,456 B
    __bf16* fc2w_bf  = (__bf16*)(ws +  9584640);      //    786,432 B
    float*  h2       = (float*) (ws + 10371072);      //      8,192 B
    float*  bb2      = (float*) (ws + 10379264);      //      8,192 B
    float*  f3       = (float*) (ws + 10387456);      //      8,192 B
    __bf16* Sred     = (__bf16*)(ws + 10395648);      //  6,291,456 B (16.69 MB total)

    proj_prep_kernel<<<1312, 256, 0, stream>>>(q_feat, g_feat, fc0w, fc0b, se,
                                               fc2w, fc2b, bn2g, bn2b, fc3w,
                                               kfragA, qfrag16, sig32, fc2w_bf,
                                               h2, bb2, f3);
    score_kernel<<<2048, 256, 0, stream>>>(kfragA, qfrag16, sig32, bn1g, bn1b, Sred);
    mlp_kernel<<<256, 512, 0, stream>>>(Sred, fc2w_bf, h2, bb2, f3,
                                        fc3b, bn3g, bn3b, out);
}

// Round 11
// 223.738 us; speedup vs baseline: 2.3997x; 1.0232x over previous
//
#include <hip/hip_runtime.h>

// Shapes (fixed by the problem)
#define LL 192
#define FF 2048

typedef __attribute__((__ext_vector_type__(8)))  __bf16 bf16x8;
typedef __attribute__((__ext_vector_type__(4)))  __bf16 bf16x4;
typedef __attribute__((__ext_vector_type__(4)))  float  f32x4;

#define MFMA16(a, b, c) __builtin_amdgcn_mfma_f32_16x16x32_bf16((a), (b), (c), 0, 0, 0)

// Empirical gfx950 laws (R1-R10 evidence):
//  - VGPR budget ~= 256 / (launch_bounds 2nd arg); VGPR_Count==budget -> spill.
//    Waves/SIMD: pool ~2048/CU, steps at vgpr {64,128,256} (R5: 244 regs ok).
//  - 256-thr blocks co-schedule by LDS; grid must exceed residency*256.
//  - R10 pipe audit: LDS pipe is the cap (~82% busy): every wave read the
//    whole 48KB K-tile (4x replication) + __shfl_xor lowers to DS ops.
//    Fix: amortize A-reads over 2 q per block; rm-reduce via DPP (VALU).

// max over lanes {x, x^1, x^2} within quads via DPP quad_perm (VALU pipe,
// not DS):  0xB1 = [1,0,3,2] (xor1), 0x4E = [2,3,0,1] (xor2).
__device__ __forceinline__ float fmax_quad(float x) {
    int xi = __builtin_bit_cast(int, x);
    float y = fmaxf(x, __builtin_bit_cast(float,
                  __builtin_amdgcn_mov_dpp(xi, 0xB1, 0xF, 0xF, true)));
    int yi = __builtin_bit_cast(int, y);
    return fmaxf(y, __builtin_bit_cast(float,
                  __builtin_amdgcn_mov_dpp(yi, 0x4E, 0xF, 0xF, true)));
}

// ---------------------------------------------------------------------------
// Kernel 1: fused projection + prep (unchanged from R10).
// ---------------------------------------------------------------------------
__launch_bounds__(256, 2)
__global__ void proj_prep_kernel(const float* __restrict__ qf_in,
                                 const float* __restrict__ gf_in,
                                 const float* __restrict__ fc0w,
                                 const float* __restrict__ fc0b,
                                 const float* __restrict__ se,
                                 const float* __restrict__ fc2w,
                                 const float* __restrict__ fc2b,
                                 const float* __restrict__ bn2g,
                                 const float* __restrict__ bn2b,
                                 const float* __restrict__ fc3w,
                                 __bf16* __restrict__ kfragA,
                                 __bf16* __restrict__ qfrag16,
                                 float* __restrict__ sig32,
                                 __bf16* __restrict__ fc2w_bf,
                                 float* __restrict__ h2,
                                 float* __restrict__ bb2,
                                 float* __restrict__ f3)
{
    int bx = blockIdx.x, tid = threadIdx.x;
    if (bx >= 1152) {
        int i0 = (bx - 1152) * 256 + tid;
        const int stride = 160 * 256;
        const float c1 = rsqrtf(1.f + 1e-5f);
        for (int i = i0; i < LL * LL; i += stride) {
            int r = i & 3, lane = (i >> 2) & 63, tile = i >> 8;
            int jt = tile % 12, st = tile / 12;
            int s = st * 16 + (lane >> 4) * 4 + r;
            int t = jt * 16 + (lane & 15);
            sig32[i] = 1.f / (1.f + __expf(-se[s * 192 + t]));
        }
        for (int i = i0; i < FF * LL; i += stride)
            fc2w_bf[i] = (__bf16)fc2w[i];
        for (int i = i0; i < FF; i += stride) {
            float h = bn2g[i] * c1;
            h2[i]  = h;
            bb2[i] = fc2b[i] * h + bn2b[i];
            f3[i]  = fc3w[i];
        }
        return;
    }
    __shared__ __bf16 Xs[32][136];
    __shared__ __bf16 Ws[128][136];
    __shared__ __bf16 Os[4096];
    const float* src = (bx < 384) ? (qf_in + (size_t)bx * (32 * 128))
                                  : (gf_in + (size_t)(bx - 384) * (32 * 128));
#pragma unroll
    for (int it = 0; it < 4; ++it) {
        int e = (it * 256 + tid) * 4;
        int r = e >> 7, c = e & 127;
        float4 v = *reinterpret_cast<const float4*>(src + e);
        bf16x4 xv;
        xv[0] = (__bf16)v.x; xv[1] = (__bf16)v.y;
        xv[2] = (__bf16)v.z; xv[3] = (__bf16)v.w;
        *reinterpret_cast<bf16x4*>(&Xs[r][c]) = xv;
    }
#pragma unroll
    for (int it = 0; it < 16; ++it) {
        int e = (it * 256 + tid) * 4;
        int r = e >> 7, c = e & 127;
        float4 v = *reinterpret_cast<const float4*>(fc0w + e);
        bf16x4 xv;
        xv[0] = (__bf16)v.x; xv[1] = (__bf16)v.y;
        xv[2] = (__bf16)v.z; xv[3] = (__bf16)v.w;
        *reinterpret_cast<bf16x4*>(&Ws[r][c]) = xv;
    }
    __syncthreads();

    int wv = tid >> 6, lane = tid & 63, quad = lane >> 4, l16 = lane & 15;
    int n0 = wv * 32;
    f32x4 acc[2][2];
#pragma unroll
    for (int m = 0; m < 2; ++m)
#pragma unroll
        for (int n = 0; n < 2; ++n) acc[m][n] = (f32x4){0.f, 0.f, 0.f, 0.f};
#pragma unroll
    for (int ks = 0; ks < 4; ++ks) {
        bf16x8 a0 = *reinterpret_cast<const bf16x8*>(&Xs[l16][ks * 32 + quad * 8]);
        bf16x8 a1 = *reinterpret_cast<const bf16x8*>(&Xs[16 + l16][ks * 32 + quad * 8]);
        bf16x8 b0 = *reinterpret_cast<const bf16x8*>(&Ws[n0 + l16][ks * 32 + quad * 8]);
        bf16x8 b1 = *reinterpret_cast<const bf16x8*>(&Ws[n0 + 16 + l16][ks * 32 + quad * 8]);
        acc[0][0] = MFMA16(a0, b0, acc[0][0]);
        acc[0][1] = MFMA16(a0, b1, acc[0][1]);
        acc[1][0] = MFMA16(a1, b0, acc[1][0]);
        acc[1][1] = MFMA16(a1, b1, acc[1][1]);
    }
#pragma unroll
    for (int mt = 0; mt < 2; ++mt)
#pragma unroll
        for (int nt = 0; nt < 2; ++nt) {
            int d = n0 + nt * 16 + l16;
            float bv = fc0b[d];
            int abase = mt * 2048 + (d >> 5) * 512 + ((d >> 3) & 3) * 128 + (d & 7);
#pragma unroll
            for (int r = 0; r < 4; ++r)
                Os[abase + (quad * 4 + r) * 8] = (__bf16)(acc[mt][nt][r] + bv);
        }
    __syncthreads();

    int row0 = bx * 32;
    __bf16* dst;
    if (bx < 384) {
        int qi = row0 / 192, tg0 = (row0 % 192) >> 4;
        dst = qfrag16 + qi * 24576 + tg0 * 2048;
    } else {
        int rk0 = row0 - 12288;
        int ki = rk0 / 192, sg0 = (rk0 % 192) >> 4;
        dst = kfragA + ki * 24576 + sg0 * 2048;
    }
#pragma unroll
    for (int it = 0; it < 2; ++it) {
        int e = (it * 256 + tid) * 8;
        *reinterpret_cast<bf16x8*>(dst + e) =
            *reinterpret_cast<const bf16x8*>(&Os[e]);
    }
}

// ---------------------------------------------------------------------------
// Kernel 2: score GEMM + sigmoid-modulation + dual max-reduce.
//    Grid 1024: block owns (q0, q0+1) x 4 keys.  256 threads = 4 waves,
//    wave w owns fixed t-slice {3w..3w+2}:
//      - B (query) frags for BOTH q hoisted (96 VGPRs, amortized 4 keys)
//      - A (key) staged per key in three 16KB thirds; each A-frag read
//        feeds MFMAs of both q -> A-LDS-reads HALVED per pair
//      - sig32 loads shared across the 2 q (halved)
//      - rm 4-lane reduce via DPP quad_perm (VALU pipe, zero DS ops)
//    ~190 VGPRs, budget 256 via (256,1) (R5: 244 ok); LDS 29.4KB.
// ---------------------------------------------------------------------------
__launch_bounds__(256, 1)
__global__ void score_kernel(const __bf16* __restrict__ kfragA,
                             const __bf16* __restrict__ qfrag16,
                             const float* __restrict__ sig32,
                             const float* __restrict__ bn1g,
                             const float* __restrict__ bn1b,
                             __bf16* __restrict__ Sred)
{
    __shared__ __bf16 Abuf[8192];          // 16,384 B: 64 s-rows of K frags
    __shared__ __bf16 rowT4[2][16][200];   // 12,800 B: row-max partials per q

    int tid = threadIdx.x;
    int q0 = (blockIdx.x & 31) * 2;
    int kbase = (blockIdx.x >> 5) << 2;    // 32 k-groups of 4 keys
    int w = tid >> 6, lane = tid & 63, quad = lane >> 4, l16 = lane & 15;
    const float g1c = bn1g[0] * rsqrtf(1.f + 1e-5f);
    const float b1v = bn1b[0];

    // Hoist B (query) fragments for both q: 2 x 12 x 4 = 96 VGPRs
    bf16x8 Bf[2][3][4];
#pragma unroll
    for (int p = 0; p < 2; ++p) {
        const __bf16* qb = qfrag16 + (size_t)(q0 + p) * 24576 + lane * 8;
#pragma unroll
        for (int j = 0; j < 3; ++j)
#pragma unroll
            for (int ks = 0; ks < 4; ++ks)
                Bf[p][j][ks] = *reinterpret_cast<const bf16x8*>(
                    qb + ((3 * w + j) * 4 + ks) * 512);
    }

#pragma unroll 1
    for (int kk = 0; kk < 4; ++kk) {
        int kidx = kbase + kk;
        const __bf16* kp = kfragA + (size_t)kidx * 24576;
        float cm[2][3];
#pragma unroll
        for (int p = 0; p < 2; ++p)
#pragma unroll
            for (int j = 0; j < 3; ++j) cm[p][j] = -3.0e38f;

#pragma unroll 1
        for (int h = 0; h < 3; ++h) {
            // stage third h: s-rows [64h, 64h+64) = 8192 bf16
#pragma unroll
            for (int it = 0; it < 4; ++it) {
                int e = (it * 256 + tid) * 8;
                *reinterpret_cast<bf16x8*>(&Abuf[e]) =
                    *reinterpret_cast<const bf16x8*>(kp + 8192 * h + e);
            }
            __syncthreads();   // Abuf ready (prev-third reads done)

#pragma unroll 1
            for (int lsc = 0; lsc < 2; ++lsc) {   // 32 s-rows per chunk
                f32x4 acc[2][2][3];               // [q][i][j]
#pragma unroll
                for (int p = 0; p < 2; ++p)
#pragma unroll
                    for (int i = 0; i < 2; ++i)
#pragma unroll
                        for (int j = 0; j < 3; ++j)
                            acc[p][i][j] = (f32x4){0.f, 0.f, 0.f, 0.f};

#pragma unroll
                for (int ks = 0; ks < 4; ++ks) {
                    bf16x8 a0 = *reinterpret_cast<const bf16x8*>(
                        &Abuf[((lsc * 2 + 0) * 4 + ks) * 512 + lane * 8]);
                    bf16x8 a1 = *reinterpret_cast<const bf16x8*>(
                        &Abuf[((lsc * 2 + 1) * 4 + ks) * 512 + lane * 8]);
#pragma unroll
                    for (int j = 0; j < 3; ++j) {
                        acc[0][0][j] = MFMA16(a0, Bf[0][j][ks], acc[0][0][j]);
                        acc[0][1][j] = MFMA16(a1, Bf[0][j][ks], acc[0][1][j]);
                        acc[1][0][j] = MFMA16(a0, Bf[1][j][ks], acc[1][0][j]);
                        acc[1][1][j] = MFMA16(a1, Bf[1][j][ks], acc[1][1][j]);
                    }
                }

                // epilogue: v = acc * sig (f32 sig shared across both q)
                //   s = 64h + lsc*32 + 16i + quad*4 + r,  t = (3w+j)*16 + l16
#pragma unroll
                for (int i = 0; i < 2; ++i) {
                    int stile = 4 * h + lsc * 2 + i;
                    const float* sp = sig32 +
                        ((size_t)(stile * 12 + 3 * w) * 64 + lane) * 4;
                    f32x4 s0 = *reinterpret_cast<const f32x4*>(sp);
                    f32x4 s1 = *reinterpret_cast<const f32x4*>(sp + 256);
                    f32x4 s2 = *reinterpret_cast<const f32x4*>(sp + 512);
#pragma unroll
                    for (int p = 0; p < 2; ++p) {
                        float v00 = acc[p][i][0][0] * s0[0];
                        float v01 = acc[p][i][0][1] * s0[1];
                        float v02 = acc[p][i][0][2] * s0[2];
                        float v03 = acc[p][i][0][3] * s0[3];
                        float v10 = acc[p][i][1][0] * s1[0];
                        float v11 = acc[p][i][1][1] * s1[1];
                        float v12 = acc[p][i][1][2] * s1[2];
                        float v13 = acc[p][i][1][3] * s1[3];
                        float v20 = acc[p][i][2][0] * s2[0];
                        float v21 = acc[p][i][2][1] * s2[1];
                        float v22 = acc[p][i][2][2] * s2[2];
                        float v23 = acc[p][i][2][3] * s2[3];
                        // row maxes over j (v_max3)
                        float rm0 = fmaxf(fmaxf(v00, v10), v20);
                        float rm1 = fmaxf(fmaxf(v01, v11), v21);
                        float rm2 = fmaxf(fmaxf(v02, v12), v22);
                        float rm3 = fmaxf(fmaxf(v03, v13), v23);
                        // col maxes over r folded into running cm
                        cm[p][0] = fmaxf(fmaxf(cm[p][0], fmaxf(v00, v01)),
                                         fmaxf(v02, v03));
                        cm[p][1] = fmaxf(fmaxf(cm[p][1], fmaxf(v10, v11)),
                                         fmaxf(v12, v13));
                        cm[p][2] = fmaxf(fmaxf(cm[p][2], fmaxf(v20, v21)),
                                         fmaxf(v22, v23));
                        // rm reduce over l16 bits 0,1 on the VALU pipe (DPP)
                        rm0 = fmax_quad(rm0);
                        rm1 = fmax_quad(rm1);
                        rm2 = fmax_quad(rm2);
                        rm3 = fmax_quad(rm3);
                        if ((l16 & 3) == 0) {
                            bf16x4 pk;
                            pk[0] = (__bf16)rm0; pk[1] = (__bf16)rm1;
                            pk[2] = (__bf16)rm2; pk[3] = (__bf16)rm3;
                            *reinterpret_cast<bf16x4*>(
                                &rowT4[p][(l16 >> 2) * 4 + w]
                                      [stile * 16 + quad * 4]) = pk;
                        }
                    }
                }
            }
            __syncthreads();   // third consumed; (h=2): rowT4 fully written
        }

        // col-max (max over s, indexed by t): reduce over quad, direct write
#pragma unroll
        for (int p = 0; p < 2; ++p) {
            size_t ob = (size_t)((q0 + p) * 128 + kidx) * 384;
            float v0 = cm[p][0], v1 = cm[p][1], v2 = cm[p][2];
            v0 = fmaxf(v0, __shfl_xor(v0, 16, 64));
            v0 = fmaxf(v0, __shfl_xor(v0, 32, 64));
            v1 = fmaxf(v1, __shfl_xor(v1, 16, 64));
            v1 = fmaxf(v1, __shfl_xor(v1, 32, 64));
            v2 = fmaxf(v2, __shfl_xor(v2, 16, 64));
            v2 = fmaxf(v2, __shfl_xor(v2, 32, 64));
            if (quad == 0) {
                Sred[ob + (3 * w + 0) * 16 + l16] = (__bf16)(v0 * g1c + b1v);
                Sred[ob + (3 * w + 1) * 16 + l16] = (__bf16)(v1 * g1c + b1v);
                Sred[ob + (3 * w + 2) * 16 + l16] = (__bf16)(v2 * g1c + b1v);
            }
        }

        // row-max combine (max over t, indexed by s) for both q; rowT4 is
        // complete per the barrier ending h=2; next key's rowT4 writes are
        // fenced by its staging barrier -> no WAR hazard.
        if (tid < 192) {
#pragma unroll
            for (int p = 0; p < 2; ++p) {
                size_t ob = (size_t)((q0 + p) * 128 + kidx) * 384;
                float m1 = -3.0e38f;
#pragma unroll
                for (int c = 0; c < 16; ++c)
                    m1 = fmaxf(m1, (float)rowT4[p][c][tid]);
                Sred[ob + 192 + tid] = (__bf16)(m1 * g1c + b1v);
            }
        }
    }
}

// ---------------------------------------------------------------------------
// Kernel 3: fused fc2 + bn2 + relu + fc3 + pair-sum + bn3 (unchanged).
// ---------------------------------------------------------------------------
__launch_bounds__(512, 1)
__global__ void mlp_kernel(const __bf16* __restrict__ Sred,
                           const __bf16* __restrict__ fc2w_bf,
                           const float* __restrict__ h2,
                           const float* __restrict__ bb2,
                           const float* __restrict__ f3,
                           const float* __restrict__ fc3b,
                           const float* __restrict__ bn3g,
                           const float* __restrict__ bn3b,
                           float* __restrict__ out)
{
    __shared__ __bf16 As[64][200];
    __shared__ float  psum_lds[8][64];
    int bx = blockIdx.x, tid = threadIdx.x;
    const __bf16* asrc = Sred + (size_t)bx * (64 * 192);
#pragma unroll
    for (int it = 0; it < 3; ++it) {
        int e = (it * 512 + tid) * 8;
        int r = e / 192, c = e - r * 192;
        *reinterpret_cast<bf16x8*>(&As[r][c]) =
            *reinterpret_cast<const bf16x8*>(asrc + e);
    }
    __syncthreads();

    int wv = tid >> 6, lane = tid & 63, quad = lane >> 4, l16 = lane & 15;
    bf16x8 af[4][6];
#pragma unroll
    for (int m = 0; m < 4; ++m)
#pragma unroll
        for (int kk = 0; kk < 6; ++kk)
            af[m][kk] = *reinterpret_cast<const bf16x8*>(
                &As[m * 16 + l16][kk * 32 + quad * 8]);

    float ps[4][4] = {{0.f,0.f,0.f,0.f},{0.f,0.f,0.f,0.f},
                      {0.f,0.f,0.f,0.f},{0.f,0.f,0.f,0.f}};
    for (int nt = 0; nt < 16; ++nt) {
        int n0 = wv * 256 + nt * 16;
        f32x4 acc[4];
#pragma unroll
        for (int m = 0; m < 4; ++m) acc[m] = (f32x4){0.f, 0.f, 0.f, 0.f};
        const __bf16* bp = fc2w_bf + (size_t)(n0 + l16) * 192 + quad * 8;
#pragma unroll
        for (int kk = 0; kk < 6; ++kk) {
            bf16x8 b = *reinterpret_cast<const bf16x8*>(bp + kk * 32);
#pragma unroll
            for (int m = 0; m < 4; ++m) acc[m] = MFMA16(af[m][kk], b, acc[m]);
        }
        int n = n0 + l16;
        float hh = h2[n], bb = bb2[n], ffv = f3[n];
#pragma unroll
        for (int m = 0; m < 4; ++m)
#pragma unroll
            for (int r = 0; r < 4; ++r)
                ps[m][r] += fmaxf(acc[m][r] * hh + bb, 0.f) * ffv;
    }
#pragma unroll
    for (int m = 0; m < 4; ++m)
#pragma unroll
        for (int r = 0; r < 4; ++r) {
            float v = ps[m][r];
            v += __shfl_xor(v, 1, 64);
            v += __shfl_xor(v, 2, 64);
            v += __shfl_xor(v, 4, 64);
            v += __shfl_xor(v, 8, 64);
            if (l16 == 0) psum_lds[wv][m * 16 + quad * 4 + r] = v;
        }
    __syncthreads();
    if (tid < 32) {
        float s = 0.f;
#pragma unroll
        for (int w = 0; w < 8; ++w)
            s += psum_lds[w][2 * tid] + psum_lds[w][2 * tid + 1];
        const float c1 = rsqrtf(1.f + 1e-5f);
        out[bx * 32 + tid] = (s + 2.f * fc3b[0]) * (bn3g[0] * c1) + bn3b[0];
    }
}

// ---------------------------------------------------------------------------
extern "C" void kernel_launch(void* const* d_in, const int* in_sizes, int n_in,
                              void* d_out, int out_size, void* d_ws, size_t ws_size,
                              hipStream_t stream)
{
    const float* q_feat = (const float*)d_in[0];
    const float* g_feat = (const float*)d_in[1];
    const float* se     = (const float*)d_in[2];
    const float* fc0w   = (const float*)d_in[3];
    const float* fc0b   = (const float*)d_in[4];
    const float* fc2w   = (const float*)d_in[5];
    const float* fc2b   = (const float*)d_in[6];
    const float* fc3w   = (const float*)d_in[7];
    const float* fc3b   = (const float*)d_in[8];
    const float* bn1g   = (const float*)d_in[9];
    const float* bn1b   = (const float*)d_in[10];
    const float* bn2g   = (const float*)d_in[11];
    const float* bn2b   = (const float*)d_in[12];
    const float* bn3g   = (const float*)d_in[13];
    const float* bn3b   = (const float*)d_in[14];
    float* out = (float*)d_out;

    char* ws = (char*)d_ws;
    __bf16* kfragA   = (__bf16*)(ws);                 //  6,291,456 B
    __bf16* qfrag16  = (__bf16*)(ws +  6291456);      //  3,145,728 B
    float*  sig32    = (float*) (ws +  9437184);      //    147,456 B
    __bf16* fc2w_bf  = (__bf16*)(ws +  9584640);      //    786,432 B
    float*  h2       = (float*) (ws + 10371072);      //      8,192 B
    float*  bb2      = (float*) (ws + 10379264);      //      8,192 B
    float*  f3       = (float*) (ws + 10387456);      //      8,192 B
    __bf16* Sred     = (__bf16*)(ws + 10395648);      //  6,291,456 B (16.69 MB total)

    proj_prep_kernel<<<1312, 256, 0, stream>>>(q_feat, g_feat, fc0w, fc0b, se,
                                               fc2w, fc2b, bn2g, bn2b, fc3w,
                                               kfragA, qfrag16, sig32, fc2w_bf,
                                               h2, bb2, f3);
    score_kernel<<<1024, 256, 0, stream>>>(kfragA, qfrag16, sig32, bn1g, bn1b, Sred);
    mlp_kernel<<<256, 512, 0, stream>>>(Sred, fc2w_bf, h2, bb2, f3,
                                        fc3b, bn3g, bn3b, out);
}